// Round 14
// baseline (298.819 us; speedup 1.0000x reference)
//
#include <hip/hip_runtime.h>

// FilterInitializerLinear: conv3x3(512->512, pad1) on (192,512,22,22) fp32,
// PrRoIPool 4x4 per (image,seq) roi, mean over 3 images, /(C*16).
// KEY ALGEBRA: pooling and conv are both linear -> pool FIRST:
//   out[s,co,pq] = (sum_K W[co,K] * G[s,K,pq] + b[co]*Sy[p]*Sx[q]) / (3*512*16)
//   G[ci,ky,kx,p,q] = sum_{u,v} wy_shift[ky][p][u] * wx_shift[kx][q][v] * F[ci][u][v]
// Round-14: ky-split pool (24-float acc, max occupancy) + img-loop INSIDE the
// block accumulating in registers -> Gpart intermediate and reduce kernel
// deleted (-113 MB traffic, -1 launch). gemm back to KQ=8 (best measured).

#define NIMG 192
#define CCH 512
#define FH 22
#define FW 22
#define SPATIAL 484
#define KDIM 4608          // pos*512 + ci
#define NDIM 1024          // s*16 + p*4 + q
#define KQ 8               // K-split factor in GEMM
#define KSEG 576           // KDIM / KQ (9 chunks of 64)

typedef __bf16 bf16;
typedef __bf16 bf16x2 __attribute__((ext_vector_type(2)));
typedef __bf16 bf16x8 __attribute__((ext_vector_type(8)));
typedef float f32x4 __attribute__((ext_vector_type(4)));

#define GLOBAL_AS __attribute__((address_space(1)))
#define LDS_AS __attribute__((address_space(3)))

__device__ __forceinline__ void gload_lds16(const void* g, void* l) {
  __builtin_amdgcn_global_load_lds((GLOBAL_AS const void*)g, (LDS_AS void*)l, 16, 0, 0);
}

// ---- prep (1 block): shifted pooling-weight tables wys_g/wxs_g[n][ky][u][p]
// (fp32, zero-padded shifts), per-image read ranges boxes[n] = {yr0,yr1,xr0,xr1},
// bias factors BF[s][16] = sum_i Sy[p]*Sx[q].
__global__ __launch_bounds__(256) void prep_kernel(const float* __restrict__ bb,
                                                   int* __restrict__ boxes,
                                                   float* __restrict__ wys_g,
                                                   float* __restrict__ wxs_g,
                                                   float* __restrict__ BF) {
  __shared__ float syl[NIMG][2][4];
  int t = threadIdx.x;
  const float scale = 1.f / 16.f;
  // zero both shifted tables (contiguous in ws: wys_g then wxs_g, 101376 floats)
  f32x4* z = (f32x4*)wys_g;
  for (int idx = t; idx < 25344; idx += 256) z[idx] = (f32x4){0.f, 0.f, 0.f, 0.f};
  if (t < NIMG) {
    int n = t;
    float x1s = bb[n * 4 + 0] * scale;
    float y1s = bb[n * 4 + 1] * scale;
    float x2s = (bb[n * 4 + 0] + bb[n * 4 + 2]) * scale;
    float y2s = (bb[n * 4 + 1] + bb[n * 4 + 3]) * scale;
    float binx = (x2s - x1s) * 0.25f;
    float biny = (y2s - y1s) * 0.25f;
    float endx = (x1s + 3 * binx) + binx;   // fp-identical to weight-fill bin-3 end
    float endy = (y1s + 3 * biny) + biny;
    int x0 = max(0, (int)floorf(x1s));
    int xc1 = min(FW - 1, (int)floorf(endx) + 1);
    int y0 = max(0, (int)floorf(y1s));
    int yc1 = min(FH - 1, (int)floorf(endy) + 1);
    int* b = boxes + n * 4;
    b[0] = max(0, y0 - 1);       // u-range (support of shifted wy)
    b[1] = min(FH - 1, yc1 + 1);
    b[2] = max(0, x0 - 1);       // v-range
    b[3] = min(FW - 1, xc1 + 1);
  }
  __syncthreads();
  // weight fill: item = (n, axis, p); each item owns distinct table entries
  #pragma unroll
  for (int k = 0; k < 6; ++k) {
    int item = t + 256 * k;   // < 1536
    int n = item >> 3;
    int axis = (item >> 2) & 1;
    int p = item & 3;
    float a0 = axis ? bb[n * 4 + 0] : bb[n * 4 + 1];
    float aw = axis ? bb[n * 4 + 2] : bb[n * 4 + 3];
    float s1 = a0 * scale;
    float s2 = (a0 + aw) * scale;
    float blen = (s2 - s1) * 0.25f;
    float start = s1 + p * blen;
    float end = start + blen;
    float inv = 1.0f / blen;           // folds 1/area
    float* tbl = (axis ? wxs_g : wys_g) + n * 264;   // [3ky][22u][4p]
    float S = 0.f;
    int s0i = (int)floorf(start);
    for (int kk = 0; kk < 6; ++kk) {
      int cell = s0i + kk;
      float cf = (float)cell;
      float a1 = fmaxf(start, cf);
      float a2 = fmaxf(fminf(end, cf + 1.f), a1);
      float alpha = a1 - cf, lim = a2 - cf;
      float f0 = (lim - 0.5f * lim * lim) - (alpha - 0.5f * alpha * alpha);
      float f1 = 0.5f * lim * lim - 0.5f * alpha * alpha;
      if (cell >= 0 && cell < 22) {
        float w = f0 * inv;
        S += w;
        #pragma unroll
        for (int ky = 0; ky < 3; ++ky) {
          int u = cell + ky - 1;
          if (u >= 0 && u < 22) tbl[(ky * 22 + u) * 4 + p] += w;
        }
      }
      if (cell + 1 >= 0 && cell + 1 < 22) {
        float w = f1 * inv;
        S += w;
        #pragma unroll
        for (int ky = 0; ky < 3; ++ky) {
          int u = cell + ky;
          if (u >= 0 && u < 22) tbl[(ky * 22 + u) * 4 + p] += w;
        }
      }
    }
    syl[n][axis][p] = S;
  }
  __syncthreads();
  #pragma unroll
  for (int k = 0; k < 4; ++k) {
    int item = t + 256 * k;   // < 1024 = s*16 + p*4 + q
    int s = item >> 4;
    int p = (item >> 2) & 3;
    int q = item & 3;
    float acc = 0.f;
    #pragma unroll
    for (int i = 0; i < 3; ++i)
      acc += syl[i * 64 + s][0][p] * syl[i * 64 + s][1][q];
    BF[item] = acc;
  }
}

// ---- cast: feat fp32 NCHW -> bf16 NHWC Ft[n][y][x][ci], restricted to the
// box read ranges. Fused: blocks [NIMG*FH, +CCH) do conv_w -> Wb[co][pos][ci].
__global__ __launch_bounds__(256) void cast_kernel(const float* __restrict__ feat,
                                                   bf16* __restrict__ Ft,
                                                   const float* __restrict__ cw,
                                                   bf16* __restrict__ Wb,
                                                   const int* __restrict__ boxes) {
  static __shared__ __align__(16) char smem[CCH * FW * 2];   // 22528 B
  int t = threadIdx.x;
  if (blockIdx.x >= NIMG * FH) {
    int co = blockIdx.x - NIMG * FH;
    float* lw = (float*)smem;
    const float* src = cw + (long)co * CCH * 9;
    #pragma unroll
    for (int k = 0; k < 18; ++k) lw[t + 256 * k] = src[t + 256 * k];
    __syncthreads();
    bf16* dst = Wb + (long)co * 9 * CCH;
    #pragma unroll
    for (int k = 0; k < 18; ++k) {
      int f = t + 256 * k;
      int pos = f >> 9;
      int ci = f & 511;
      dst[f] = (bf16)lw[ci * 9 + pos];
    }
    return;
  }
  bf16* lt = (bf16*)smem;   // [ci][x]
  int n = blockIdx.x / FH;
  int y = blockIdx.x % FH;
  int yr0 = boxes[n * 4 + 0], yr1 = boxes[n * 4 + 1];
  if (y < yr0 || y > yr1) return;
  int xr0 = boxes[n * 4 + 2], xr1 = boxes[n * 4 + 3];
  const float* fb = feat + (long)n * CCH * SPATIAL + y * FW;
  #pragma unroll 4
  for (int k = 0; k < 44; ++k) {            // 512*22 = 11264 = 256*44
    int f = t + 256 * k;
    int ci = f / FW;
    int x = f - ci * FW;
    if (x >= xr0 && x <= xr1) lt[f] = (bf16)fb[(long)ci * SPATIAL + x];
  }
  __syncthreads();
  uint* od = (uint*)(Ft + ((long)(n * FH + y) * FW) * CCH);
  int ci = t * 2;
  for (int px = xr0; px <= xr1; ++px) {
    bf16x2 pr;
    pr[0] = lt[ci * FW + px];
    pr[1] = lt[(ci + 1) * FW + px];
    od[px * 256 + t] = __builtin_bit_cast(uint, pr);
  }
}

// ---- pool_feat: separable PrRoI pooling of features, summed over 3 images
// in registers -> Gb[N=s*16+pq][K=pos*512+ci] bf16 DIRECTLY (no Gpart).
// Grid 768 = (s 64) x (ciq 4) x (ky 3); 256 threads = (lci 64, p 4);
// lane owns a ci PAIR (uint load), 4-deep dynamic u batching.
// acc = 24 floats/thread -> launch_bounds(256,8): max occupancy.
__global__ __launch_bounds__(256, 8) void pool_feat_kernel(
    const bf16* __restrict__ Ft, const int* __restrict__ boxes,
    const float* __restrict__ wys_g, const float* __restrict__ wxs_g,
    bf16* __restrict__ Gb) {
  __shared__ float wyk[88];     // this ky's shifted row for current img: [22u][4p]
  __shared__ float wxl[264];    // [3kx][22v][4q] for current img
  int bid = blockIdx.x;
  int ky = bid % 3;
  int rest = bid / 3;
  int ciq = rest & 3;
  int s = rest >> 2;
  int t = threadIdx.x;
  int p = t >> 6;                 // wave-uniform
  int lci = t & 63;
  int ci = ciq * 128 + lci * 2;

  f32x4 A0[3], A1[3];   // [kx] over q; A0 = ci, A1 = ci+1; summed over imgs
  #pragma unroll
  for (int a = 0; a < 3; ++a) {
    A0[a] = (f32x4){0.f, 0.f, 0.f, 0.f};
    A1[a] = (f32x4){0.f, 0.f, 0.f, 0.f};
  }
  const f32x4* wxp = (const f32x4*)wxl;

  for (int img = 0; img < 3; ++img) {
    int n = img * 64 + s;
    __syncthreads();   // previous-img readers done before overwrite
    for (int idx = t; idx < 352; idx += 256) {
      if (idx < 88) wyk[idx] = wys_g[n * 264 + ky * 88 + idx];
      else wxl[idx - 88] = wxs_g[n * 264 + idx - 88];
    }
    __syncthreads();
    int yr0 = boxes[n * 4 + 0], yr1 = boxes[n * 4 + 1];
    int xr0 = boxes[n * 4 + 2], xr1 = boxes[n * 4 + 3];
    // Ft as uint (ci pairs): elem (u,v) at [(u*FW+v)*256 + ciq*64 + lci]
    const uint* base = (const uint*)Ft + (long)n * FH * FW * 256 + ciq * 64 + lci;

#define PROC(BU, UU)                                                     \
    {                                                                    \
      bf16x2 pr = __builtin_bit_cast(bf16x2, (BU));                      \
      float w = wyk[(UU) * 4 + p];                                       \
      ay0 = fmaf(w, (float)pr[0], ay0);                                  \
      ay1 = fmaf(w, (float)pr[1], ay1);                                  \
    }

    for (int v = xr0; v <= xr1; ++v) {
      const uint* colp = base + v * 256;
      float ay0 = 0.f, ay1 = 0.f;
      int u = yr0;
      for (; u + 3 <= yr1; u += 4) {          // 4 independent loads in flight
        uint b0 = colp[(long)u * 5632];
        uint b1 = colp[(long)(u + 1) * 5632];
        uint b2 = colp[(long)(u + 2) * 5632];
        uint b3 = colp[(long)(u + 3) * 5632];
        PROC(b0, u); PROC(b1, u + 1); PROC(b2, u + 2); PROC(b3, u + 3);
      }
      for (; u <= yr1; ++u) {
        uint b0 = colp[(long)u * 5632];
        PROC(b0, u);
      }
      #pragma unroll
      for (int kx = 0; kx < 3; ++kx) {
        f32x4 wx4 = wxp[kx * 22 + v];
        A0[kx] += wx4 * ay0;
        A1[kx] += wx4 * ay1;
      }
    }
#undef PROC
  }

  // write Gb bf16 directly (disjoint per (s, ciq, ky) -> no races)
  #pragma unroll
  for (int kx = 0; kx < 3; ++kx) {
    #pragma unroll
    for (int q = 0; q < 4; ++q) {
      long off = (long)(s * 16 + p * 4 + q) * KDIM + (ky * 3 + kx) * CCH + ci;
      bf16x2 o;
      o[0] = (bf16)A0[kx][q];
      o[1] = (bf16)A1[kx][q];
      *(bf16x2*)(Gb + off) = o;
    }
  }
}

// ---- gemm: Opart[kq][co 512][n 1024] = W[co][k]*Gb[n][k] over k-segment.
// 256 blocks = 4 mt x 8 nt x 8 kq; 128x128 tile, 4 waves, BK=64, 9 chunks,
// proven staging + both-sides XOR swizzle.
__global__ __launch_bounds__(256, 2) void gemm_kernel(const bf16* __restrict__ Wb,
                                                      const bf16* __restrict__ Gb,
                                                      float* __restrict__ Opart) {
  __shared__ __align__(16) bf16 As[128 * 64];
  __shared__ __align__(16) bf16 Bs[128 * 64];
  int bid = blockIdx.x;
  int kq = bid & 7;
  int nt = (bid >> 3) & 7;
  int mt = bid >> 6;
  int co0 = mt << 7;
  int n0 = nt << 7;
  int kbase = kq * KSEG;

  int tid = threadIdx.x;
  int wv = tid >> 6, l = tid & 63;
  int wm = wv >> 1, wn = wv & 1;
  int lrow = l >> 3;
  int cg8 = ((l & 7) ^ lrow) << 3;

  long aOff[4], bOff[4];
  #pragma unroll
  for (int j = 0; j < 4; ++j) {
    int row = j * 32 + wv * 8 + lrow;
    aOff[j] = (long)(co0 + row) * KDIM + kbase + cg8;
    bOff[j] = (long)(n0 + row) * KDIM + kbase + cg8;
  }

  const f32x4 vz = {0.f, 0.f, 0.f, 0.f};
  f32x4 acc[4][4];
  #pragma unroll
  for (int a = 0; a < 4; ++a)
    #pragma unroll
    for (int b = 0; b < 4; ++b) acc[a][b] = vz;

  for (int c = 0; c < 9; ++c) {
    long sh = c * 64;
    #pragma unroll
    for (int j = 0; j < 4; ++j) {
      gload_lds16(Wb + aOff[j] + sh, (char*)As + (j * 32 + wv * 8) * 128);
      gload_lds16(Gb + bOff[j] + sh, (char*)Bs + (j * 32 + wv * 8) * 128);
    }
    __syncthreads();
    bf16x8 af[2][4], bfv[2][4];
    #pragma unroll
    for (int kk = 0; kk < 2; ++kk) {
      #pragma unroll
      for (int i = 0; i < 4; ++i) {
        int rowa = wm * 64 + i * 16 + (l & 15);
        int offa = rowa * 128 + kk * 64 + ((l >> 4) * 16);
        offa ^= (rowa & 7) << 4;
        af[kk][i] = *(const bf16x8*)((const char*)As + offa);
        int rowb = wn * 64 + i * 16 + (l & 15);
        int offb = rowb * 128 + kk * 64 + ((l >> 4) * 16);
        offb ^= (rowb & 7) << 4;
        bfv[kk][i] = *(const bf16x8*)((const char*)Bs + offb);
      }
    }
    #pragma unroll
    for (int kk = 0; kk < 2; ++kk)
      #pragma unroll
      for (int mi = 0; mi < 4; ++mi)
        #pragma unroll
        for (int nj = 0; nj < 4; ++nj)
          acc[mi][nj] = __builtin_amdgcn_mfma_f32_16x16x32_bf16(
              af[kk][mi], bfv[kk][nj], acc[mi][nj], 0, 0, 0);
    __syncthreads();
  }

  // C/D layout: col=lane&15 (n), row=(lane>>4)*4+reg (co)
  float* op = Opart + (long)kq * CCH * NDIM;
  #pragma unroll
  for (int nj = 0; nj < 4; ++nj) {
    int nn = n0 + wn * 64 + nj * 16 + (l & 15);
    #pragma unroll
    for (int mi = 0; mi < 4; ++mi) {
      #pragma unroll
      for (int rr = 0; rr < 4; ++rr) {
        int co = co0 + wm * 64 + mi * 16 + (l >> 4) * 4 + rr;
        op[(long)co * NDIM + nn] = acc[mi][nj][rr];
      }
    }
  }
}

// ---- epilogue: out[s][co][pq] = (sum_kq Opart + b[co]*BF[s][pq]) * fin
__global__ __launch_bounds__(256) void epi_kernel(const float* __restrict__ Opart,
                                                  const float* __restrict__ BF,
                                                  const float* __restrict__ cb,
                                                  float* __restrict__ out) {
  int t4 = blockIdx.x * 256 + threadIdx.x;   // 131072 threads, 4 floats each
  int base = t4 * 4;                         // = s*8192 + co*16 + pqc
  int s = base >> 13;
  int co = (base >> 4) & 511;
  int pqc = base & 15;
  long osrc = (long)co * NDIM + s * 16 + pqc;
  f32x4 v = *(const f32x4*)(Opart + osrc);
  #pragma unroll
  for (int kq = 1; kq < KQ; ++kq)
    v += *(const f32x4*)(Opart + (long)kq * CCH * NDIM + osrc);
  f32x4 bf4 = *(const f32x4*)(BF + s * 16 + pqc);
  const float fin = 1.f / (3.f * 512.f * 16.f);
  v = (v + cb[co] * bf4) * fin;
  *(f32x4*)(out + base) = v;
}

extern "C" void kernel_launch(void* const* d_in, const int* in_sizes, int n_in,
                              void* d_out, int out_size, void* d_ws, size_t ws_size,
                              hipStream_t stream) {
  const float* feat = (const float*)d_in[0];
  const float* bb = (const float*)d_in[1];
  const float* cw = (const float*)d_in[2];
  const float* cb = (const float*)d_in[3];
  float* out = (float*)d_out;

  const size_t FT_BYTES = (size_t)NIMG * FH * FW * CCH * 2;     //  95,158,272
  const size_t WB_BYTES = (size_t)CCH * 9 * CCH * 2;            //   4,718,592
  const size_t GB_BYTES = (size_t)NDIM * KDIM * 2;              //   9,437,184
  const size_t OP_BYTES = (size_t)KQ * CCH * NDIM * 4;          //  16,777,216
  const size_t WT_BYTES = (size_t)NIMG * 264 * 4;               //     202,752 (x2)
  const size_t BF_BYTES = 64 * 16 * 4;
  const size_t BOX_BYTES = NIMG * 4 * 4;
  if (ws_size < FT_BYTES + WB_BYTES + GB_BYTES + OP_BYTES + 2 * WT_BYTES +
                    BF_BYTES + BOX_BYTES)
    return;

  char* ws = (char*)d_ws;
  bf16* Ft = (bf16*)ws;
  bf16* Wb = (bf16*)(ws + FT_BYTES);
  bf16* Gb = (bf16*)(ws + FT_BYTES + WB_BYTES);
  float* Opart = (float*)(ws + FT_BYTES + WB_BYTES + GB_BYTES);
  float* wys_g = (float*)(ws + FT_BYTES + WB_BYTES + GB_BYTES + OP_BYTES);
  float* wxs_g = wys_g + NIMG * 264;
  float* BF = wxs_g + NIMG * 264;
  int* boxes = (int*)(BF + 64 * 16);

  hipLaunchKernelGGL(prep_kernel, dim3(1), dim3(256), 0, stream, bb, boxes, wys_g,
                     wxs_g, BF);
  hipLaunchKernelGGL(cast_kernel, dim3(NIMG * FH + CCH), dim3(256), 0, stream,
                     feat, Ft, cw, Wb, boxes);
  hipLaunchKernelGGL(pool_feat_kernel, dim3(768), dim3(256), 0, stream, Ft, boxes,
                     wys_g, wxs_g, Gb);
  hipLaunchKernelGGL(gemm_kernel, dim3(256), dim3(256), 0, stream, Wb, Gb, Opart);
  hipLaunchKernelGGL(epi_kernel, dim3(512), dim3(256), 0, stream, Opart, BF, cb, out);
}

// Round 15
// 188.855 us; speedup vs baseline: 1.5823x; 1.5823x over previous
//
#include <hip/hip_runtime.h>

// FilterInitializerLinear: conv3x3(512->512, pad1) on (192,512,22,22) fp32,
// PrRoIPool 4x4 per (image,seq) roi, mean over 3 images, /(C*16).
// KEY ALGEBRA: pooling and conv are both linear -> pool FIRST:
//   out[s,co,pq] = (sum_K W[co,K] * G[s,K,pq] + b[co]*Sy[p]*Sx[q]) / (3*512*16)
//   G[ci,ky,kx,p,q] = sum_{u,v} wy_shift[ky][p][u] * wx_shift[kx][q][v] * F[ci][u][v]
// Round-15: pool_feat reads were latency-bound in every reg-batched variant
// (55-160us vs ~15us traffic floor). Fix the MECHANISM: bulk-stage the box
// tile into LDS via global_load_lds (1KB/instr, per-lane global gather,
// linear LDS dest), compute from LDS. img loop inside -> Gb direct, no Gpart.

#define NIMG 192
#define CCH 512
#define FH 22
#define FW 22
#define SPATIAL 484
#define KDIM 4608          // pos*512 + ci
#define NDIM 1024          // s*16 + p*4 + q
#define KQ 8               // K-split factor in GEMM
#define KSEG 576           // KDIM / KQ (9 chunks of 64)

typedef __bf16 bf16;
typedef __bf16 bf16x2 __attribute__((ext_vector_type(2)));
typedef __bf16 bf16x8 __attribute__((ext_vector_type(8)));
typedef float f32x4 __attribute__((ext_vector_type(4)));

#define GLOBAL_AS __attribute__((address_space(1)))
#define LDS_AS __attribute__((address_space(3)))

__device__ __forceinline__ void gload_lds16(const void* g, void* l) {
  __builtin_amdgcn_global_load_lds((GLOBAL_AS const void*)g, (LDS_AS void*)l, 16, 0, 0);
}

// ---- prep (1 block): shifted pooling-weight tables wys_g/wxs_g[n][ky][u][p]
// (fp32, zero-padded shifts), per-image read ranges boxes[n] = {yr0,yr1,xr0,xr1},
// bias factors BF[s][16] = sum_i Sy[p]*Sx[q].
__global__ __launch_bounds__(256) void prep_kernel(const float* __restrict__ bb,
                                                   int* __restrict__ boxes,
                                                   float* __restrict__ wys_g,
                                                   float* __restrict__ wxs_g,
                                                   float* __restrict__ BF) {
  __shared__ float syl[NIMG][2][4];
  int t = threadIdx.x;
  const float scale = 1.f / 16.f;
  // zero both shifted tables (contiguous in ws: wys_g then wxs_g, 101376 floats)
  f32x4* z = (f32x4*)wys_g;
  for (int idx = t; idx < 25344; idx += 256) z[idx] = (f32x4){0.f, 0.f, 0.f, 0.f};
  if (t < NIMG) {
    int n = t;
    float x1s = bb[n * 4 + 0] * scale;
    float y1s = bb[n * 4 + 1] * scale;
    float x2s = (bb[n * 4 + 0] + bb[n * 4 + 2]) * scale;
    float y2s = (bb[n * 4 + 1] + bb[n * 4 + 3]) * scale;
    float binx = (x2s - x1s) * 0.25f;
    float biny = (y2s - y1s) * 0.25f;
    float endx = (x1s + 3 * binx) + binx;   // fp-identical to weight-fill bin-3 end
    float endy = (y1s + 3 * biny) + biny;
    int x0 = max(0, (int)floorf(x1s));
    int xc1 = min(FW - 1, (int)floorf(endx) + 1);
    int y0 = max(0, (int)floorf(y1s));
    int yc1 = min(FH - 1, (int)floorf(endy) + 1);
    int* b = boxes + n * 4;
    b[0] = max(0, y0 - 1);       // u-range (support of shifted wy)
    b[1] = min(FH - 1, yc1 + 1);
    b[2] = max(0, x0 - 1);       // v-range
    b[3] = min(FW - 1, xc1 + 1);
  }
  __syncthreads();
  // weight fill: item = (n, axis, p); each item owns distinct table entries
  #pragma unroll
  for (int k = 0; k < 6; ++k) {
    int item = t + 256 * k;   // < 1536
    int n = item >> 3;
    int axis = (item >> 2) & 1;
    int p = item & 3;
    float a0 = axis ? bb[n * 4 + 0] : bb[n * 4 + 1];
    float aw = axis ? bb[n * 4 + 2] : bb[n * 4 + 3];
    float s1 = a0 * scale;
    float s2 = (a0 + aw) * scale;
    float blen = (s2 - s1) * 0.25f;
    float start = s1 + p * blen;
    float end = start + blen;
    float inv = 1.0f / blen;           // folds 1/area
    float* tbl = (axis ? wxs_g : wys_g) + n * 264;   // [3ky][22u][4p]
    float S = 0.f;
    int s0i = (int)floorf(start);
    for (int kk = 0; kk < 6; ++kk) {
      int cell = s0i + kk;
      float cf = (float)cell;
      float a1 = fmaxf(start, cf);
      float a2 = fmaxf(fminf(end, cf + 1.f), a1);
      float alpha = a1 - cf, lim = a2 - cf;
      float f0 = (lim - 0.5f * lim * lim) - (alpha - 0.5f * alpha * alpha);
      float f1 = 0.5f * lim * lim - 0.5f * alpha * alpha;
      if (cell >= 0 && cell < 22) {
        float w = f0 * inv;
        S += w;
        #pragma unroll
        for (int ky = 0; ky < 3; ++ky) {
          int u = cell + ky - 1;
          if (u >= 0 && u < 22) tbl[(ky * 22 + u) * 4 + p] += w;
        }
      }
      if (cell + 1 >= 0 && cell + 1 < 22) {
        float w = f1 * inv;
        S += w;
        #pragma unroll
        for (int ky = 0; ky < 3; ++ky) {
          int u = cell + ky;
          if (u >= 0 && u < 22) tbl[(ky * 22 + u) * 4 + p] += w;
        }
      }
    }
    syl[n][axis][p] = S;
  }
  __syncthreads();
  #pragma unroll
  for (int k = 0; k < 4; ++k) {
    int item = t + 256 * k;   // < 1024 = s*16 + p*4 + q
    int s = item >> 4;
    int p = (item >> 2) & 3;
    int q = item & 3;
    float acc = 0.f;
    #pragma unroll
    for (int i = 0; i < 3; ++i)
      acc += syl[i * 64 + s][0][p] * syl[i * 64 + s][1][q];
    BF[item] = acc;
  }
}

// ---- cast: feat fp32 NCHW -> bf16 NHWC Ft[n][y][x][ci], restricted to the
// box read ranges. Fused: blocks [NIMG*FH, +CCH) do conv_w -> Wb[co][pos][ci].
__global__ __launch_bounds__(256) void cast_kernel(const float* __restrict__ feat,
                                                   bf16* __restrict__ Ft,
                                                   const float* __restrict__ cw,
                                                   bf16* __restrict__ Wb,
                                                   const int* __restrict__ boxes) {
  static __shared__ __align__(16) char smem[CCH * FW * 2];   // 22528 B
  int t = threadIdx.x;
  if (blockIdx.x >= NIMG * FH) {
    int co = blockIdx.x - NIMG * FH;
    float* lw = (float*)smem;
    const float* src = cw + (long)co * CCH * 9;
    #pragma unroll
    for (int k = 0; k < 18; ++k) lw[t + 256 * k] = src[t + 256 * k];
    __syncthreads();
    bf16* dst = Wb + (long)co * 9 * CCH;
    #pragma unroll
    for (int k = 0; k < 18; ++k) {
      int f = t + 256 * k;
      int pos = f >> 9;
      int ci = f & 511;
      dst[f] = (bf16)lw[ci * 9 + pos];
    }
    return;
  }
  bf16* lt = (bf16*)smem;   // [ci][x]
  int n = blockIdx.x / FH;
  int y = blockIdx.x % FH;
  int yr0 = boxes[n * 4 + 0], yr1 = boxes[n * 4 + 1];
  if (y < yr0 || y > yr1) return;
  int xr0 = boxes[n * 4 + 2], xr1 = boxes[n * 4 + 3];
  const float* fb = feat + (long)n * CCH * SPATIAL + y * FW;
  #pragma unroll 4
  for (int k = 0; k < 44; ++k) {            // 512*22 = 11264 = 256*44
    int f = t + 256 * k;
    int ci = f / FW;
    int x = f - ci * FW;
    if (x >= xr0 && x <= xr1) lt[f] = (bf16)fb[(long)ci * SPATIAL + x];
  }
  __syncthreads();
  uint* od = (uint*)(Ft + ((long)(n * FH + y) * FW) * CCH);
  int ci = t * 2;
  for (int px = xr0; px <= xr1; ++px) {
    bf16x2 pr;
    pr[0] = lt[ci * FW + px];
    pr[1] = lt[(ci + 1) * FW + px];
    od[px * 256 + t] = __builtin_bit_cast(uint, pr);
  }
}

// ---- pool_feat: separable PrRoI pooling, summed over 3 images in registers
// -> Gb[N=s*16+pq][K=pos*512+ci] bf16 directly.
// Grid 256 = (s 64) x (ciq 4), 1 block/CU; 256 threads = (lci 64, p 4).
// Per image: bulk-stage the box tile (up to 22x22 cells x 128ci bf16 = 124KB)
// into LDS via global_load_lds (1KB/instr: per-lane global gather of 4 cells,
// linear LDS dest), then compute from LDS (64-consecutive-uint reads/wave =
// 2-way bank alias = free). acc = 72 floats (9 pos x q-vec x 2ci).
__global__ __launch_bounds__(256) void pool_feat_kernel(
    const bf16* __restrict__ Ft, const int* __restrict__ boxes,
    const float* __restrict__ wys_g, const float* __restrict__ wxs_g,
    bf16* __restrict__ Gb) {
  __shared__ __align__(16) bf16 tile[496 * 128];   // 126,976 B (484 cells max)
  __shared__ float wyl[264];    // [3ky][22u][4p] current img
  __shared__ float wxl[264];    // [3kx][22v][4q] current img
  int s = blockIdx.x >> 2;
  int ciq = blockIdx.x & 3;
  int t = threadIdx.x;
  int wv = t >> 6;                // wave id == p
  int p = wv;
  int lci = t & 63;               // lane owns ci pair (ci = ciq*128 + lci*2)

  f32x4 A0[9], A1[9];   // [pos = ky*3+kx] over q; summed over imgs
  #pragma unroll
  for (int a = 0; a < 9; ++a) {
    A0[a] = (f32x4){0.f, 0.f, 0.f, 0.f};
    A1[a] = (f32x4){0.f, 0.f, 0.f, 0.f};
  }
  const f32x4* wxp = (const f32x4*)wxl;
  const uint* tu = (const uint*)tile;

  for (int img = 0; img < 3; ++img) {
    int n = img * 64 + s;
    __syncthreads();   // previous-img compute done before overwrite
    for (int idx = t; idx < 528; idx += 256) {
      if (idx < 264) wyl[idx] = wys_g[n * 264 + idx];
      else wxl[idx - 264] = wxs_g[n * 264 + idx - 264];
    }
    int yr0 = boxes[n * 4 + 0], yr1 = boxes[n * 4 + 1];
    int xr0 = boxes[n * 4 + 2], xr1 = boxes[n * 4 + 3];
    int yh = yr1 - yr0 + 1;
    int xw = xr1 - xr0 + 1;
    int ncells = yh * xw;
    int nch = (ncells + 3) >> 2;        // 1KB chunks (4 cells each)
    const bf16* fbase = Ft + (long)n * FH * FW * CCH + ciq * 128 + (lci & 15) * 8;
    for (int c = wv; c < nch; c += 4) {  // waves stripe chunks
      int idx = c * 4 + (lci >> 4);
      if (idx > ncells - 1) idx = ncells - 1;   // tail: dup cell into pad slot
      int r = idx / xw;
      int x = idx - r * xw;
      const bf16* src = fbase + ((long)(yr0 + r) * FW + (xr0 + x)) * CCH;
      gload_lds16(src, (char*)tile + c * 1024);
    }
    __syncthreads();   // drains global_load_lds (compiler emits vmcnt(0))

    for (int v = 0; v < xw; ++v) {
      float a00 = 0.f, a01 = 0.f, a10 = 0.f, a11 = 0.f, a20 = 0.f, a21 = 0.f;
#define PROC(BU, UU)                                                     \
      {                                                                  \
        bf16x2 pr = __builtin_bit_cast(bf16x2, (BU));                    \
        float f0 = (float)pr[0], f1 = (float)pr[1];                      \
        float w0 = wyl[(UU) * 4 + p];                                    \
        float w1 = wyl[(22 + (UU)) * 4 + p];                             \
        float w2 = wyl[(44 + (UU)) * 4 + p];                             \
        a00 = fmaf(w0, f0, a00); a01 = fmaf(w0, f1, a01);                \
        a10 = fmaf(w1, f0, a10); a11 = fmaf(w1, f1, a11);                \
        a20 = fmaf(w2, f0, a20); a21 = fmaf(w2, f1, a21);                \
      }
      int r = 0;
      for (; r + 3 < yh; r += 4) {
        uint b0 = tu[(r * xw + v) * 64 + lci];
        uint b1 = tu[((r + 1) * xw + v) * 64 + lci];
        uint b2 = tu[((r + 2) * xw + v) * 64 + lci];
        uint b3 = tu[((r + 3) * xw + v) * 64 + lci];
        PROC(b0, yr0 + r); PROC(b1, yr0 + r + 1);
        PROC(b2, yr0 + r + 2); PROC(b3, yr0 + r + 3);
      }
      for (; r < yh; ++r) {
        uint b0 = tu[(r * xw + v) * 64 + lci];
        PROC(b0, yr0 + r);
      }
#undef PROC
      int va = xr0 + v;   // absolute v for weight table
      #pragma unroll
      for (int kx = 0; kx < 3; ++kx) {
        f32x4 wx4 = wxp[kx * 22 + va];
        A0[kx] += wx4 * a00; A1[kx] += wx4 * a01;
        A0[3 + kx] += wx4 * a10; A1[3 + kx] += wx4 * a11;
        A0[6 + kx] += wx4 * a20; A1[6 + kx] += wx4 * a21;
      }
    }
  }

  int ci = ciq * 128 + lci * 2;
  #pragma unroll
  for (int pos = 0; pos < 9; ++pos) {
    #pragma unroll
    for (int q = 0; q < 4; ++q) {
      long off = (long)(s * 16 + p * 4 + q) * KDIM + pos * CCH + ci;
      bf16x2 o;
      o[0] = (bf16)A0[pos][q];
      o[1] = (bf16)A1[pos][q];
      *(bf16x2*)(Gb + off) = o;
    }
  }
}

// ---- gemm: Opart[kq][co 512][n 1024] = W[co][k]*Gb[n][k] over k-segment.
// 256 blocks = 4 mt x 8 nt x 8 kq; 128x128 tile, 4 waves, BK=64, 9 chunks,
// proven staging + both-sides XOR swizzle.
__global__ __launch_bounds__(256, 2) void gemm_kernel(const bf16* __restrict__ Wb,
                                                      const bf16* __restrict__ Gb,
                                                      float* __restrict__ Opart) {
  __shared__ __align__(16) bf16 As[128 * 64];
  __shared__ __align__(16) bf16 Bs[128 * 64];
  int bid = blockIdx.x;
  int kq = bid & 7;
  int nt = (bid >> 3) & 7;
  int mt = bid >> 6;
  int co0 = mt << 7;
  int n0 = nt << 7;
  int kbase = kq * KSEG;

  int tid = threadIdx.x;
  int wv = tid >> 6, l = tid & 63;
  int wm = wv >> 1, wn = wv & 1;
  int lrow = l >> 3;
  int cg8 = ((l & 7) ^ lrow) << 3;

  long aOff[4], bOff[4];
  #pragma unroll
  for (int j = 0; j < 4; ++j) {
    int row = j * 32 + wv * 8 + lrow;
    aOff[j] = (long)(co0 + row) * KDIM + kbase + cg8;
    bOff[j] = (long)(n0 + row) * KDIM + kbase + cg8;
  }

  const f32x4 vz = {0.f, 0.f, 0.f, 0.f};
  f32x4 acc[4][4];
  #pragma unroll
  for (int a = 0; a < 4; ++a)
    #pragma unroll
    for (int b = 0; b < 4; ++b) acc[a][b] = vz;

  for (int c = 0; c < 9; ++c) {
    long sh = c * 64;
    #pragma unroll
    for (int j = 0; j < 4; ++j) {
      gload_lds16(Wb + aOff[j] + sh, (char*)As + (j * 32 + wv * 8) * 128);
      gload_lds16(Gb + bOff[j] + sh, (char*)Bs + (j * 32 + wv * 8) * 128);
    }
    __syncthreads();
    bf16x8 af[2][4], bfv[2][4];
    #pragma unroll
    for (int kk = 0; kk < 2; ++kk) {
      #pragma unroll
      for (int i = 0; i < 4; ++i) {
        int rowa = wm * 64 + i * 16 + (l & 15);
        int offa = rowa * 128 + kk * 64 + ((l >> 4) * 16);
        offa ^= (rowa & 7) << 4;
        af[kk][i] = *(const bf16x8*)((const char*)As + offa);
        int rowb = wn * 64 + i * 16 + (l & 15);
        int offb = rowb * 128 + kk * 64 + ((l >> 4) * 16);
        offb ^= (rowb & 7) << 4;
        bfv[kk][i] = *(const bf16x8*)((const char*)Bs + offb);
      }
    }
    #pragma unroll
    for (int kk = 0; kk < 2; ++kk)
      #pragma unroll
      for (int mi = 0; mi < 4; ++mi)
        #pragma unroll
        for (int nj = 0; nj < 4; ++nj)
          acc[mi][nj] = __builtin_amdgcn_mfma_f32_16x16x32_bf16(
              af[kk][mi], bfv[kk][nj], acc[mi][nj], 0, 0, 0);
    __syncthreads();
  }

  // C/D layout: col=lane&15 (n), row=(lane>>4)*4+reg (co)
  float* op = Opart + (long)kq * CCH * NDIM;
  #pragma unroll
  for (int nj = 0; nj < 4; ++nj) {
    int nn = n0 + wn * 64 + nj * 16 + (l & 15);
    #pragma unroll
    for (int mi = 0; mi < 4; ++mi) {
      #pragma unroll
      for (int rr = 0; rr < 4; ++rr) {
        int co = co0 + wm * 64 + mi * 16 + (l >> 4) * 4 + rr;
        op[(long)co * NDIM + nn] = acc[mi][nj][rr];
      }
    }
  }
}

// ---- epilogue: out[s][co][pq] = (sum_kq Opart + b[co]*BF[s][pq]) * fin
__global__ __launch_bounds__(256) void epi_kernel(const float* __restrict__ Opart,
                                                  const float* __restrict__ BF,
                                                  const float* __restrict__ cb,
                                                  float* __restrict__ out) {
  int t4 = blockIdx.x * 256 + threadIdx.x;   // 131072 threads, 4 floats each
  int base = t4 * 4;                         // = s*8192 + co*16 + pqc
  int s = base >> 13;
  int co = (base >> 4) & 511;
  int pqc = base & 15;
  long osrc = (long)co * NDIM + s * 16 + pqc;
  f32x4 v = *(const f32x4*)(Opart + osrc);
  #pragma unroll
  for (int kq = 1; kq < KQ; ++kq)
    v += *(const f32x4*)(Opart + (long)kq * CCH * NDIM + osrc);
  f32x4 bf4 = *(const f32x4*)(BF + s * 16 + pqc);
  const float fin = 1.f / (3.f * 512.f * 16.f);
  v = (v + cb[co] * bf4) * fin;
  *(f32x4*)(out + base) = v;
}

extern "C" void kernel_launch(void* const* d_in, const int* in_sizes, int n_in,
                              void* d_out, int out_size, void* d_ws, size_t ws_size,
                              hipStream_t stream) {
  const float* feat = (const float*)d_in[0];
  const float* bb = (const float*)d_in[1];
  const float* cw = (const float*)d_in[2];
  const float* cb = (const float*)d_in[3];
  float* out = (float*)d_out;

  const size_t FT_BYTES = (size_t)NIMG * FH * FW * CCH * 2;     //  95,158,272
  const size_t WB_BYTES = (size_t)CCH * 9 * CCH * 2;            //   4,718,592
  const size_t GB_BYTES = (size_t)NDIM * KDIM * 2;              //   9,437,184
  const size_t OP_BYTES = (size_t)KQ * CCH * NDIM * 4;          //  16,777,216
  const size_t WT_BYTES = (size_t)NIMG * 264 * 4;               //     202,752 (x2)
  const size_t BF_BYTES = 64 * 16 * 4;
  const size_t BOX_BYTES = NIMG * 4 * 4;
  if (ws_size < FT_BYTES + WB_BYTES + GB_BYTES + OP_BYTES + 2 * WT_BYTES +
                    BF_BYTES + BOX_BYTES)
    return;

  char* ws = (char*)d_ws;
  bf16* Ft = (bf16*)ws;
  bf16* Wb = (bf16*)(ws + FT_BYTES);
  bf16* Gb = (bf16*)(ws + FT_BYTES + WB_BYTES);
  float* Opart = (float*)(ws + FT_BYTES + WB_BYTES + GB_BYTES);
  float* wys_g = (float*)(ws + FT_BYTES + WB_BYTES + GB_BYTES + OP_BYTES);
  float* wxs_g = wys_g + NIMG * 264;
  float* BF = wxs_g + NIMG * 264;
  int* boxes = (int*)(BF + 64 * 16);

  hipLaunchKernelGGL(prep_kernel, dim3(1), dim3(256), 0, stream, bb, boxes, wys_g,
                     wxs_g, BF);
  hipLaunchKernelGGL(cast_kernel, dim3(NIMG * FH + CCH), dim3(256), 0, stream,
                     feat, Ft, cw, Wb, boxes);
  hipLaunchKernelGGL(pool_feat_kernel, dim3(256), dim3(256), 0, stream, Ft, boxes,
                     wys_g, wxs_g, Gb);
  hipLaunchKernelGGL(gemm_kernel, dim3(256), dim3(256), 0, stream, Wb, Gb, Opart);
  hipLaunchKernelGGL(epi_kernel, dim3(512), dim3(256), 0, stream, Opart, BF, cb, out);
}

// Round 16
// 120.148 us; speedup vs baseline: 2.4871x; 1.5719x over previous
//
#include <hip/hip_runtime.h>

// FilterInitializerLinear: conv3x3(512->512, pad1) on (192,512,22,22) fp32,
// PrRoIPool 4x4 per (image,seq) roi, mean over 3 images, /(C*16).
// KEY ALGEBRA: pool FIRST (both ops linear):
//   out[s,co,pq] = (sum_K W[co,K] * G[s,K,pq] + b[co]*Sy[p]*Sx[q]) / (3*512*16)
//   G[ci,ky,kx,p,q] = sum_{u,v} wy_shift[ky][p][u] * wx_shift[kx][q][v] * F[ci][u][v]
// Round-16: prep_kernel DELETED (its global-RMW weight fill was ~20-40us) --
// cast computes boxes inline, pool builds weight tables in LDS, epi computes
// bias factors inline. Pool: 64-ci slices -> 62KB tile -> 2 blocks/CU.

#define NIMG 192
#define CCH 512
#define FH 22
#define FW 22
#define SPATIAL 484
#define KDIM 4608          // pos*512 + ci
#define NDIM 1024          // s*16 + p*4 + q
#define KQ 8               // K-split factor in GEMM
#define KSEG 576           // KDIM / KQ (9 chunks of 64)

typedef __bf16 bf16;
typedef __bf16 bf16x2 __attribute__((ext_vector_type(2)));
typedef __bf16 bf16x8 __attribute__((ext_vector_type(8)));
typedef float f32x4 __attribute__((ext_vector_type(4)));

#define GLOBAL_AS __attribute__((address_space(1)))
#define LDS_AS __attribute__((address_space(3)))

__device__ __forceinline__ void gload_lds16(const void* g, void* l) {
  __builtin_amdgcn_global_load_lds((GLOBAL_AS const void*)g, (LDS_AS void*)l, 16, 0, 0);
}

// Extended read range [r0, r1] for one axis (fp-identical everywhere).
__device__ __forceinline__ void axis_range(float a0, float aw, int& r0, int& r1) {
  const float scale = 1.f / 16.f;
  float s1 = a0 * scale;
  float s2 = (a0 + aw) * scale;
  float bl = (s2 - s1) * 0.25f;
  float endv = (s1 + 3 * bl) + bl;
  int c0 = max(0, (int)floorf(s1));
  int c1 = min(21, (int)floorf(endv) + 1);
  r0 = max(0, c0 - 1);
  r1 = min(21, c1 + 1);
}

// Sum of pooling weights for one (axis, bin) -- for the bias term.
__device__ __forceinline__ float axis_sum(float a0, float aw, int bin) {
  const float scale = 1.f / 16.f;
  float s1 = a0 * scale;
  float s2 = (a0 + aw) * scale;
  float blen = (s2 - s1) * 0.25f;
  float start = s1 + bin * blen;
  float end = start + blen;
  float inv = 1.0f / blen;
  float S = 0.f;
  int s0i = (int)floorf(start);
  for (int kk = 0; kk < 6; ++kk) {
    int cell = s0i + kk;
    float cf = (float)cell;
    float a1 = fmaxf(start, cf);
    float a2 = fmaxf(fminf(end, cf + 1.f), a1);
    float alpha = a1 - cf, lim = a2 - cf;
    float f0 = (lim - 0.5f * lim * lim) - (alpha - 0.5f * alpha * alpha);
    float f1 = 0.5f * lim * lim - 0.5f * alpha * alpha;
    if (cell >= 0 && cell < 22) S += f0 * inv;
    if (cell + 1 >= 0 && cell + 1 < 22) S += f1 * inv;
  }
  return S;
}

// ---- cast: feat fp32 NCHW -> bf16 NHWC Ft[n][y][x][ci], restricted to the
// box read ranges (computed inline from bb). Fused: blocks [NIMG*FH, +CCH)
// do conv_w -> Wb[co][pos][ci].
__global__ __launch_bounds__(256) void cast_kernel(const float* __restrict__ feat,
                                                   bf16* __restrict__ Ft,
                                                   const float* __restrict__ cw,
                                                   bf16* __restrict__ Wb,
                                                   const float* __restrict__ bb) {
  static __shared__ __align__(16) char smem[CCH * FW * 2];   // 22528 B
  int t = threadIdx.x;
  if (blockIdx.x >= NIMG * FH) {
    int co = blockIdx.x - NIMG * FH;
    float* lw = (float*)smem;
    const float* src = cw + (long)co * CCH * 9;
    #pragma unroll
    for (int k = 0; k < 18; ++k) lw[t + 256 * k] = src[t + 256 * k];
    __syncthreads();
    bf16* dst = Wb + (long)co * 9 * CCH;
    #pragma unroll
    for (int k = 0; k < 18; ++k) {
      int f = t + 256 * k;
      int pos = f >> 9;
      int ci = f & 511;
      dst[f] = (bf16)lw[ci * 9 + pos];
    }
    return;
  }
  bf16* lt = (bf16*)smem;   // [ci][x]
  int n = blockIdx.x / FH;
  int y = blockIdx.x % FH;
  int yr0, yr1, xr0, xr1;
  axis_range(bb[n * 4 + 1], bb[n * 4 + 3], yr0, yr1);
  if (y < yr0 || y > yr1) return;
  axis_range(bb[n * 4 + 0], bb[n * 4 + 2], xr0, xr1);
  const float* fb = feat + (long)n * CCH * SPATIAL + y * FW;
  #pragma unroll 4
  for (int k = 0; k < 44; ++k) {            // 512*22 = 11264 = 256*44
    int f = t + 256 * k;
    int ci = f / FW;
    int x = f - ci * FW;
    if (x >= xr0 && x <= xr1) lt[f] = (bf16)fb[(long)ci * SPATIAL + x];
  }
  __syncthreads();
  uint* od = (uint*)(Ft + ((long)(n * FH + y) * FW) * CCH);
  int ci = t * 2;
  for (int px = xr0; px <= xr1; ++px) {
    bf16x2 pr;
    pr[0] = lt[ci * FW + px];
    pr[1] = lt[(ci + 1) * FW + px];
    od[px * 256 + t] = __builtin_bit_cast(uint, pr);
  }
}

// ---- pool_feat: separable PrRoI pooling, summed over 3 images in registers
// -> Gb[N=s*16+pq][K=pos*512+ci] bf16 directly.
// Grid 512 = (s 64) x (ciq 8): 64-ci slices -> tile 62KB -> 2 blocks/CU.
// 256 threads = 4 waves; wave = p, lane = ci within the 64-slice.
// Per image: bulk-stage box tile into LDS via global_load_lds (1KB/instr,
// per-lane global gather, linear LDS dest), build weight tables in LDS
// (threads 0-7, LDS RMW), compute from LDS.
__global__ __launch_bounds__(256) void pool_feat_kernel(
    const bf16* __restrict__ Ft, const float* __restrict__ bb,
    bf16* __restrict__ Gb) {
  __shared__ __align__(16) bf16 tile[488 * 64];   // 62,464 B (61 chunks max)
  __shared__ float wyl[264];    // [3ky][22u][4p] current img
  __shared__ float wxl[264];    // [3kx][22v][4q] current img
  int s = blockIdx.x >> 3;
  int ciq = blockIdx.x & 7;
  int t = threadIdx.x;
  int p = t >> 6;                 // wave id == p
  int lane = t & 63;              // single ci: ci = ciq*64 + lane

  f32x4 A[9];   // [pos = ky*3+kx] over q; summed over imgs
  #pragma unroll
  for (int a = 0; a < 9; ++a) A[a] = (f32x4){0.f, 0.f, 0.f, 0.f};
  const f32x4* wxp = (const f32x4*)wxl;
  const ushort* tu = (const ushort*)tile;

  for (int img = 0; img < 3; ++img) {
    int n = img * 64 + s;
    int yr0, yr1, xr0, xr1;
    axis_range(bb[n * 4 + 1], bb[n * 4 + 3], yr0, yr1);
    axis_range(bb[n * 4 + 0], bb[n * 4 + 2], xr0, xr1);
    int yh = yr1 - yr0 + 1;
    int xw = xr1 - xr0 + 1;
    int ncells = yh * xw;
    int nch = (ncells + 7) >> 3;        // 1KB chunks (8 cells each)
    __syncthreads();   // previous-img compute done before overwrite
    // issue bulk staging first (latency overlaps the weight-table build)
    const bf16* fb = Ft + (long)n * FH * FW * CCH + ciq * 64 + (lane & 7) * 8;
    for (int c = p; c < nch; c += 4) {  // waves stripe chunks; c wave-uniform
      int idx = c * 8 + (lane >> 3);
      if (idx > ncells - 1) idx = ncells - 1;   // tail: dup cell into pad slot
      int r = idx / xw;
      int x = idx - r * xw;
      gload_lds16(fb + ((long)(yr0 + r) * FW + (xr0 + x)) * CCH,
                  (char*)tile + c * 1024);
    }
    // zero weight tables
    for (int idx = t; idx < 528; idx += 256)
      (idx < 264 ? wyl[idx] : wxl[idx - 264]) = 0.f;
    __syncthreads();
    // fill shifted tables: threads 0-7 = (axis, bin); LDS RMW (fast)
    if (t < 8) {
      int axis = t >> 2;
      int bin = t & 3;
      const float scale = 1.f / 16.f;
      float a0 = axis ? bb[n * 4 + 0] : bb[n * 4 + 1];
      float aw = axis ? bb[n * 4 + 2] : bb[n * 4 + 3];
      float s1 = a0 * scale;
      float s2 = (a0 + aw) * scale;
      float blen = (s2 - s1) * 0.25f;
      float start = s1 + bin * blen;
      float end = start + blen;
      float inv = 1.0f / blen;
      float* tbl = axis ? wxl : wyl;
      int s0i = (int)floorf(start);
      for (int kk = 0; kk < 6; ++kk) {
        int cell = s0i + kk;
        float cf = (float)cell;
        float a1 = fmaxf(start, cf);
        float a2 = fmaxf(fminf(end, cf + 1.f), a1);
        float alpha = a1 - cf, lim = a2 - cf;
        float f0 = (lim - 0.5f * lim * lim) - (alpha - 0.5f * alpha * alpha);
        float f1 = 0.5f * lim * lim - 0.5f * alpha * alpha;
        if (cell >= 0 && cell < 22) {
          float w = f0 * inv;
          #pragma unroll
          for (int ky = 0; ky < 3; ++ky) {
            int u = cell + ky - 1;
            if (u >= 0 && u < 22) tbl[(ky * 22 + u) * 4 + bin] += w;
          }
        }
        if (cell + 1 >= 0 && cell + 1 < 22) {
          float w = f1 * inv;
          #pragma unroll
          for (int ky = 0; ky < 3; ++ky) {
            int u = cell + ky;
            if (u >= 0 && u < 22) tbl[(ky * 22 + u) * 4 + bin] += w;
          }
        }
      }
    }
    __syncthreads();   // staging drained + tables ready

    for (int v = 0; v < xw; ++v) {
      float ay0 = 0.f, ay1 = 0.f, ay2 = 0.f;
#define PROC(BU, UU)                                                     \
      {                                                                  \
        float f = (float)__builtin_bit_cast(bf16, (ushort)(BU));         \
        ay0 = fmaf(wyl[(UU) * 4 + p], f, ay0);                           \
        ay1 = fmaf(wyl[(22 + (UU)) * 4 + p], f, ay1);                    \
        ay2 = fmaf(wyl[(44 + (UU)) * 4 + p], f, ay2);                    \
      }
      int r = 0;
      for (; r + 3 < yh; r += 4) {
        ushort b0 = tu[(r * xw + v) * 64 + lane];
        ushort b1 = tu[((r + 1) * xw + v) * 64 + lane];
        ushort b2 = tu[((r + 2) * xw + v) * 64 + lane];
        ushort b3 = tu[((r + 3) * xw + v) * 64 + lane];
        PROC(b0, yr0 + r); PROC(b1, yr0 + r + 1);
        PROC(b2, yr0 + r + 2); PROC(b3, yr0 + r + 3);
      }
      for (; r < yh; ++r) {
        ushort b0 = tu[(r * xw + v) * 64 + lane];
        PROC(b0, yr0 + r);
      }
#undef PROC
      int va = xr0 + v;   // absolute v for weight table
      #pragma unroll
      for (int kx = 0; kx < 3; ++kx) {
        f32x4 wx4 = wxp[kx * 22 + va];
        A[kx] += wx4 * ay0;
        A[3 + kx] += wx4 * ay1;
        A[6 + kx] += wx4 * ay2;
      }
    }
  }

  int ci = ciq * 64 + lane;
  #pragma unroll
  for (int pos = 0; pos < 9; ++pos) {
    #pragma unroll
    for (int q = 0; q < 4; ++q) {
      Gb[(long)(s * 16 + p * 4 + q) * KDIM + pos * CCH + ci] = (bf16)A[pos][q];
    }
  }
}

// ---- gemm: Opart[kq][co 512][n 1024] = W[co][k]*Gb[n][k] over k-segment.
// 256 blocks = 4 mt x 8 nt x 8 kq; 128x128 tile, 4 waves, BK=64, 9 chunks,
// proven staging + both-sides XOR swizzle.
__global__ __launch_bounds__(256, 2) void gemm_kernel(const bf16* __restrict__ Wb,
                                                      const bf16* __restrict__ Gb,
                                                      float* __restrict__ Opart) {
  __shared__ __align__(16) bf16 As[128 * 64];
  __shared__ __align__(16) bf16 Bs[128 * 64];
  int bid = blockIdx.x;
  int kq = bid & 7;
  int nt = (bid >> 3) & 7;
  int mt = bid >> 6;
  int co0 = mt << 7;
  int n0 = nt << 7;
  int kbase = kq * KSEG;

  int tid = threadIdx.x;
  int wv = tid >> 6, l = tid & 63;
  int wm = wv >> 1, wn = wv & 1;
  int lrow = l >> 3;
  int cg8 = ((l & 7) ^ lrow) << 3;

  long aOff[4], bOff[4];
  #pragma unroll
  for (int j = 0; j < 4; ++j) {
    int row = j * 32 + wv * 8 + lrow;
    aOff[j] = (long)(co0 + row) * KDIM + kbase + cg8;
    bOff[j] = (long)(n0 + row) * KDIM + kbase + cg8;
  }

  const f32x4 vz = {0.f, 0.f, 0.f, 0.f};
  f32x4 acc[4][4];
  #pragma unroll
  for (int a = 0; a < 4; ++a)
    #pragma unroll
    for (int b = 0; b < 4; ++b) acc[a][b] = vz;

  for (int c = 0; c < 9; ++c) {
    long sh = c * 64;
    #pragma unroll
    for (int j = 0; j < 4; ++j) {
      gload_lds16(Wb + aOff[j] + sh, (char*)As + (j * 32 + wv * 8) * 128);
      gload_lds16(Gb + bOff[j] + sh, (char*)Bs + (j * 32 + wv * 8) * 128);
    }
    __syncthreads();
    bf16x8 af[2][4], bfv[2][4];
    #pragma unroll
    for (int kk = 0; kk < 2; ++kk) {
      #pragma unroll
      for (int i = 0; i < 4; ++i) {
        int rowa = wm * 64 + i * 16 + (l & 15);
        int offa = rowa * 128 + kk * 64 + ((l >> 4) * 16);
        offa ^= (rowa & 7) << 4;
        af[kk][i] = *(const bf16x8*)((const char*)As + offa);
        int rowb = wn * 64 + i * 16 + (l & 15);
        int offb = rowb * 128 + kk * 64 + ((l >> 4) * 16);
        offb ^= (rowb & 7) << 4;
        bfv[kk][i] = *(const bf16x8*)((const char*)Bs + offb);
      }
    }
    #pragma unroll
    for (int kk = 0; kk < 2; ++kk)
      #pragma unroll
      for (int mi = 0; mi < 4; ++mi)
        #pragma unroll
        for (int nj = 0; nj < 4; ++nj)
          acc[mi][nj] = __builtin_amdgcn_mfma_f32_16x16x32_bf16(
              af[kk][mi], bfv[kk][nj], acc[mi][nj], 0, 0, 0);
    __syncthreads();
  }

  // C/D layout: col=lane&15 (n), row=(lane>>4)*4+reg (co)
  float* op = Opart + (long)kq * CCH * NDIM;
  #pragma unroll
  for (int nj = 0; nj < 4; ++nj) {
    int nn = n0 + wn * 64 + nj * 16 + (l & 15);
    #pragma unroll
    for (int mi = 0; mi < 4; ++mi) {
      #pragma unroll
      for (int rr = 0; rr < 4; ++rr) {
        int co = co0 + wm * 64 + mi * 16 + (l >> 4) * 4 + rr;
        op[(long)co * NDIM + nn] = acc[mi][nj][rr];
      }
    }
  }
}

// ---- epilogue: out[s][co][pq] = (sum_kq Opart + b[co]*BF(s,p,q)) * fin
// BF computed inline from bb (identical arithmetic to the old prep table).
__global__ __launch_bounds__(256) void epi_kernel(const float* __restrict__ Opart,
                                                  const float* __restrict__ bb,
                                                  const float* __restrict__ cb,
                                                  float* __restrict__ out) {
  int t4 = blockIdx.x * 256 + threadIdx.x;   // 131072 threads, 4 floats each
  int base = t4 * 4;                         // = s*8192 + co*16 + p*4 (+q lanes)
  int s = base >> 13;
  int co = (base >> 4) & 511;
  int p = (base >> 2) & 3;
  long osrc = (long)co * NDIM + s * 16 + p * 4;
  f32x4 v = *(const f32x4*)(Opart + osrc);
  #pragma unroll
  for (int kq = 1; kq < KQ; ++kq)
    v += *(const f32x4*)(Opart + (long)kq * CCH * NDIM + osrc);
  f32x4 bf4 = {0.f, 0.f, 0.f, 0.f};
  #pragma unroll
  for (int i = 0; i < 3; ++i) {
    int n = i * 64 + s;
    float Sy = axis_sum(bb[n * 4 + 1], bb[n * 4 + 3], p);
    #pragma unroll
    for (int q = 0; q < 4; ++q)
      bf4[q] += Sy * axis_sum(bb[n * 4 + 0], bb[n * 4 + 2], q);
  }
  const float fin = 1.f / (3.f * 512.f * 16.f);
  v = (v + cb[co] * bf4) * fin;
  *(f32x4*)(out + base) = v;
}

extern "C" void kernel_launch(void* const* d_in, const int* in_sizes, int n_in,
                              void* d_out, int out_size, void* d_ws, size_t ws_size,
                              hipStream_t stream) {
  const float* feat = (const float*)d_in[0];
  const float* bb = (const float*)d_in[1];
  const float* cw = (const float*)d_in[2];
  const float* cb = (const float*)d_in[3];
  float* out = (float*)d_out;

  const size_t FT_BYTES = (size_t)NIMG * FH * FW * CCH * 2;     //  95,158,272
  const size_t WB_BYTES = (size_t)CCH * 9 * CCH * 2;            //   4,718,592
  const size_t GB_BYTES = (size_t)NDIM * KDIM * 2;              //   9,437,184
  const size_t OP_BYTES = (size_t)KQ * CCH * NDIM * 4;          //  16,777,216
  if (ws_size < FT_BYTES + WB_BYTES + GB_BYTES + OP_BYTES) return;

  char* ws = (char*)d_ws;
  bf16* Ft = (bf16*)ws;
  bf16* Wb = (bf16*)(ws + FT_BYTES);
  bf16* Gb = (bf16*)(ws + FT_BYTES + WB_BYTES);
  float* Opart = (float*)(ws + FT_BYTES + WB_BYTES + GB_BYTES);

  hipLaunchKernelGGL(cast_kernel, dim3(NIMG * FH + CCH), dim3(256), 0, stream,
                     feat, Ft, cw, Wb, bb);
  hipLaunchKernelGGL(pool_feat_kernel, dim3(512), dim3(256), 0, stream, Ft, bb, Gb);
  hipLaunchKernelGGL(gemm_kernel, dim3(256), dim3(256), 0, stream, Wb, Gb, Opart);
  hipLaunchKernelGGL(epi_kernel, dim3(512), dim3(256), 0, stream, Opart, bb, cb, out);
}

// Round 17
// 107.656 us; speedup vs baseline: 2.7757x; 1.1160x over previous
//
#include <hip/hip_runtime.h>

// FilterInitializerLinear: conv3x3(512->512, pad1) on (192,512,22,22) fp32,
// PrRoIPool 4x4 per (image,seq) roi, mean over 3 images, /(C*16).
// KEY ALGEBRA: pool FIRST (both ops linear):
//   out[s,co,pq] = (sum_K W[co,K] * G[s,K,pq] + b[co]*Sy[p]*Sx[q]) / (3*512*16)
//   G[ci,ky,kx,p,q] = sum_{u,v} wy_shift[ky][p][u] * wx_shift[kx][q][v] * F[ci][u][v]
// Round-17: cast/Ft stage DELETED. Each ci plane of feat is one contiguous
// 1936B run -> pool bulk-stages fp32 planes directly via global_load_lds
// (2x1KB per ci, 16B-aligned incl. the 912-offset tail, 112B benign overlap)
// and pools from LDS. Kills 88MB of Ft traffic + a launch; fp32-accurate pooling.

#define NIMG 192
#define CCH 512
#define FH 22
#define FW 22
#define SPATIAL 484
#define KDIM 4608          // pos*512 + ci
#define NDIM 1024          // s*16 + p*4 + q
#define KQ 8               // K-split factor in GEMM
#define KSEG 576           // KDIM / KQ (9 chunks of 64)
#define CISTRIDE 1968      // per-ci LDS bytes (1936 + 32 pad -> 4-way bank alias)

typedef __bf16 bf16;
typedef __bf16 bf16x2 __attribute__((ext_vector_type(2)));
typedef __bf16 bf16x8 __attribute__((ext_vector_type(8)));
typedef float f32x4 __attribute__((ext_vector_type(4)));

#define GLOBAL_AS __attribute__((address_space(1)))
#define LDS_AS __attribute__((address_space(3)))

__device__ __forceinline__ void gload_lds16(const void* g, void* l) {
  __builtin_amdgcn_global_load_lds((GLOBAL_AS const void*)g, (LDS_AS void*)l, 16, 0, 0);
}

// Extended read range [r0, r1] for one axis (fp-identical everywhere).
__device__ __forceinline__ void axis_range(float a0, float aw, int& r0, int& r1) {
  const float scale = 1.f / 16.f;
  float s1 = a0 * scale;
  float s2 = (a0 + aw) * scale;
  float bl = (s2 - s1) * 0.25f;
  float endv = (s1 + 3 * bl) + bl;
  int c0 = max(0, (int)floorf(s1));
  int c1 = min(21, (int)floorf(endv) + 1);
  r0 = max(0, c0 - 1);
  r1 = min(21, c1 + 1);
}

// Sum of pooling weights for one (axis, bin) -- for the bias term.
__device__ __forceinline__ float axis_sum(float a0, float aw, int bin) {
  const float scale = 1.f / 16.f;
  float s1 = a0 * scale;
  float s2 = (a0 + aw) * scale;
  float blen = (s2 - s1) * 0.25f;
  float start = s1 + bin * blen;
  float end = start + blen;
  float inv = 1.0f / blen;
  float S = 0.f;
  int s0i = (int)floorf(start);
  for (int kk = 0; kk < 6; ++kk) {
    int cell = s0i + kk;
    float cf = (float)cell;
    float a1 = fmaxf(start, cf);
    float a2 = fmaxf(fminf(end, cf + 1.f), a1);
    float alpha = a1 - cf, lim = a2 - cf;
    float f0 = (lim - 0.5f * lim * lim) - (alpha - 0.5f * alpha * alpha);
    float f1 = 0.5f * lim * lim - 0.5f * alpha * alpha;
    if (cell >= 0 && cell < 22) S += f0 * inv;
    if (cell + 1 >= 0 && cell + 1 < 22) S += f1 * inv;
  }
  return S;
}

// ---- wtrans: conv_w (co,ci,3,3) fp32 -> Wb[co][pos][ci] bf16, via LDS ----
__global__ __launch_bounds__(256) void wtrans_kernel(const float* __restrict__ cw,
                                                     bf16* __restrict__ Wb) {
  __shared__ float lw[CCH * 9];
  int co = blockIdx.x;
  int t = threadIdx.x;
  const float* src = cw + (long)co * CCH * 9;
  #pragma unroll
  for (int k = 0; k < 18; ++k) lw[t + 256 * k] = src[t + 256 * k];
  __syncthreads();
  bf16* dst = Wb + (long)co * 9 * CCH;
  #pragma unroll
  for (int k = 0; k < 18; ++k) {
    int f = t + 256 * k;
    int pos = f >> 9;
    int ci = f & 511;
    dst[f] = (bf16)lw[ci * 9 + pos];
  }
}

// ---- pool_feat: separable PrRoI pooling DIRECT from fp32 NCHW feat,
// summed over 3 images in registers -> Gb[N=s*16+pq][K=pos*512+ci] bf16.
// Grid 512 = (s 64) x (ciq 8); 512 threads = 8 waves: lane=ci (64 within
// slice), wave = (p 4, vhalf 2). Per image: stage 64 full ci planes
// (1936B contiguous each) into LDS via global_load_lds -- 2 x 1KB per ci,
// both 16B-aligned (plane=121*16, tail offset 912=57*16; 112B overlap is
// benign). Compute from LDS (stride 492 dw = 4-way alias, free-ish);
// cross-vhalf reduce via LDS scratch overlaid on the dead tile.
__global__ __launch_bounds__(512) void pool_feat_kernel(
    const float* __restrict__ feat, const float* __restrict__ bb,
    bf16* __restrict__ Gb) {
  __shared__ __align__(16) char tileb[64 * CISTRIDE];   // 125,952 B
  __shared__ float wyl[264];    // [3ky][22u][4p] current img
  __shared__ float wxl[264];    // [3kx][22v][4q] current img
  int s = blockIdx.x >> 3;
  int ciq = blockIdx.x & 7;
  int t = threadIdx.x;
  int wv = t >> 6;
  int lane = t & 63;              // ci within slice
  int p = wv & 3;
  int vh = wv >> 2;

  f32x4 A[9];   // [pos = ky*3+kx] over q; summed over imgs (this p, vhalf)
  #pragma unroll
  for (int a = 0; a < 9; ++a) A[a] = (f32x4){0.f, 0.f, 0.f, 0.f};
  const f32x4* wxp = (const f32x4*)wxl;
  const float* tf = (const float*)tileb;

  for (int img = 0; img < 3; ++img) {
    int n = img * 64 + s;
    __syncthreads();   // previous-img compute done before overwrite
    // stage 64 ci planes: 128 instructions striped over 8 waves
    for (int c = wv; c < 128; c += 8) {   // c wave-uniform
      int ci = c >> 1;
      int off = (c & 1) ? 912 : 0;
      const char* src =
          (const char*)(feat + (long)(n * CCH + ciq * 64 + ci) * SPATIAL) + off;
      gload_lds16(src + lane * 16, tileb + ci * CISTRIDE + off + lane * 16);
    }
    // zero weight tables (different LDS region; safe while staging in flight)
    for (int idx = t; idx < 528; idx += 512)
      (idx < 264 ? wyl[idx] : wxl[idx - 264]) = 0.f;
    __syncthreads();   // drains staging (vmcnt(0) before barrier) + zeros done
    // fill shifted tables: threads 0-7 = (axis, bin); LDS RMW
    if (t < 8) {
      int axis = t >> 2;
      int bin = t & 3;
      const float scale = 1.f / 16.f;
      float a0 = axis ? bb[n * 4 + 0] : bb[n * 4 + 1];
      float aw = axis ? bb[n * 4 + 2] : bb[n * 4 + 3];
      float s1 = a0 * scale;
      float s2 = (a0 + aw) * scale;
      float blen = (s2 - s1) * 0.25f;
      float start = s1 + bin * blen;
      float end = start + blen;
      float inv = 1.0f / blen;
      float* tbl = axis ? wxl : wyl;
      int s0i = (int)floorf(start);
      for (int kk = 0; kk < 6; ++kk) {
        int cell = s0i + kk;
        float cf = (float)cell;
        float a1 = fmaxf(start, cf);
        float a2 = fmaxf(fminf(end, cf + 1.f), a1);
        float alpha = a1 - cf, lim = a2 - cf;
        float f0 = (lim - 0.5f * lim * lim) - (alpha - 0.5f * alpha * alpha);
        float f1 = 0.5f * lim * lim - 0.5f * alpha * alpha;
        if (cell >= 0 && cell < 22) {
          float w = f0 * inv;
          #pragma unroll
          for (int ky = 0; ky < 3; ++ky) {
            int u = cell + ky - 1;
            if (u >= 0 && u < 22) tbl[(ky * 22 + u) * 4 + bin] += w;
          }
        }
        if (cell + 1 >= 0 && cell + 1 < 22) {
          float w = f1 * inv;
          #pragma unroll
          for (int ky = 0; ky < 3; ++ky) {
            int u = cell + ky;
            if (u >= 0 && u < 22) tbl[(ky * 22 + u) * 4 + bin] += w;
          }
        }
      }
    }
    __syncthreads();   // tables ready

    int yr0, yr1, xr0, xr1;
    axis_range(bb[n * 4 + 1], bb[n * 4 + 3], yr0, yr1);
    axis_range(bb[n * 4 + 0], bb[n * 4 + 2], xr0, xr1);
    int yh = yr1 - yr0 + 1;
    int xw = xr1 - xr0 + 1;
    int xmid = xr0 + ((xw + 1) >> 1);
    int v0 = vh ? xmid : xr0;
    int v1 = vh ? xr1 : xmid - 1;
    const float* pl = tf + lane * (CISTRIDE / 4);   // this lane's ci plane

    for (int v = v0; v <= v1; ++v) {
      float ay0 = 0.f, ay1 = 0.f, ay2 = 0.f;
#define PROC(FV, UU)                                                     \
      {                                                                  \
        ay0 = fmaf(wyl[(UU) * 4 + p], (FV), ay0);                        \
        ay1 = fmaf(wyl[(22 + (UU)) * 4 + p], (FV), ay1);                 \
        ay2 = fmaf(wyl[(44 + (UU)) * 4 + p], (FV), ay2);                 \
      }
      int u = yr0;
      for (; u + 3 <= yr1; u += 4) {
        float f0 = pl[u * FW + v];
        float f1 = pl[(u + 1) * FW + v];
        float f2 = pl[(u + 2) * FW + v];
        float f3 = pl[(u + 3) * FW + v];
        PROC(f0, u); PROC(f1, u + 1); PROC(f2, u + 2); PROC(f3, u + 3);
      }
      for (; u <= yr1; ++u) {
        float f0 = pl[u * FW + v];
        PROC(f0, u);
      }
#undef PROC
      #pragma unroll
      for (int kx = 0; kx < 3; ++kx) {
        f32x4 wx4 = wxp[kx * 22 + v];
        A[kx] += wx4 * ay0;
        A[3 + kx] += wx4 * ay1;
        A[6 + kx] += wx4 * ay2;
      }
    }
  }

  // cross-vhalf reduction via scratch overlaid on the (dead) tile
  __syncthreads();
  float* scr = (float*)tileb;   // [p][lane][36]
  if (vh == 1) {
    #pragma unroll
    for (int pos = 0; pos < 9; ++pos)
      #pragma unroll
      for (int q = 0; q < 4; ++q)
        scr[(p * 64 + lane) * 36 + pos * 4 + q] = A[pos][q];
  }
  __syncthreads();
  if (vh == 0) {
    int ci = ciq * 64 + lane;
    #pragma unroll
    for (int pos = 0; pos < 9; ++pos) {
      #pragma unroll
      for (int q = 0; q < 4; ++q) {
        float val = A[pos][q] + scr[(p * 64 + lane) * 36 + pos * 4 + q];
        Gb[(long)(s * 16 + p * 4 + q) * KDIM + pos * CCH + ci] = (bf16)val;
      }
    }
  }
}

// ---- gemm: Opart[kq][co 512][n 1024] = W[co][k]*Gb[n][k] over k-segment.
// 256 blocks = 4 mt x 8 nt x 8 kq; 128x128 tile, 4 waves, BK=64, 9 chunks,
// proven staging + both-sides XOR swizzle.
__global__ __launch_bounds__(256, 2) void gemm_kernel(const bf16* __restrict__ Wb,
                                                      const bf16* __restrict__ Gb,
                                                      float* __restrict__ Opart) {
  __shared__ __align__(16) bf16 As[128 * 64];
  __shared__ __align__(16) bf16 Bs[128 * 64];
  int bid = blockIdx.x;
  int kq = bid & 7;
  int nt = (bid >> 3) & 7;
  int mt = bid >> 6;
  int co0 = mt << 7;
  int n0 = nt << 7;
  int kbase = kq * KSEG;

  int tid = threadIdx.x;
  int wv = tid >> 6, l = tid & 63;
  int wm = wv >> 1, wn = wv & 1;
  int lrow = l >> 3;
  int cg8 = ((l & 7) ^ lrow) << 3;

  long aOff[4], bOff[4];
  #pragma unroll
  for (int j = 0; j < 4; ++j) {
    int row = j * 32 + wv * 8 + lrow;
    aOff[j] = (long)(co0 + row) * KDIM + kbase + cg8;
    bOff[j] = (long)(n0 + row) * KDIM + kbase + cg8;
  }

  const f32x4 vz = {0.f, 0.f, 0.f, 0.f};
  f32x4 acc[4][4];
  #pragma unroll
  for (int a = 0; a < 4; ++a)
    #pragma unroll
    for (int b = 0; b < 4; ++b) acc[a][b] = vz;

  for (int c = 0; c < 9; ++c) {
    long sh = c * 64;
    #pragma unroll
    for (int j = 0; j < 4; ++j) {
      gload_lds16(Wb + aOff[j] + sh, (char*)As + (j * 32 + wv * 8) * 128);
      gload_lds16(Gb + bOff[j] + sh, (char*)Bs + (j * 32 + wv * 8) * 128);
    }
    __syncthreads();
    bf16x8 af[2][4], bfv[2][4];
    #pragma unroll
    for (int kk = 0; kk < 2; ++kk) {
      #pragma unroll
      for (int i = 0; i < 4; ++i) {
        int rowa = wm * 64 + i * 16 + (l & 15);
        int offa = rowa * 128 + kk * 64 + ((l >> 4) * 16);
        offa ^= (rowa & 7) << 4;
        af[kk][i] = *(const bf16x8*)((const char*)As + offa);
        int rowb = wn * 64 + i * 16 + (l & 15);
        int offb = rowb * 128 + kk * 64 + ((l >> 4) * 16);
        offb ^= (rowb & 7) << 4;
        bfv[kk][i] = *(const bf16x8*)((const char*)Bs + offb);
      }
    }
    #pragma unroll
    for (int kk = 0; kk < 2; ++kk)
      #pragma unroll
      for (int mi = 0; mi < 4; ++mi)
        #pragma unroll
        for (int nj = 0; nj < 4; ++nj)
          acc[mi][nj] = __builtin_amdgcn_mfma_f32_16x16x32_bf16(
              af[kk][mi], bfv[kk][nj], acc[mi][nj], 0, 0, 0);
    __syncthreads();
  }

  // C/D layout: col=lane&15 (n), row=(lane>>4)*4+reg (co)
  float* op = Opart + (long)kq * CCH * NDIM;
  #pragma unroll
  for (int nj = 0; nj < 4; ++nj) {
    int nn = n0 + wn * 64 + nj * 16 + (l & 15);
    #pragma unroll
    for (int mi = 0; mi < 4; ++mi) {
      #pragma unroll
      for (int rr = 0; rr < 4; ++rr) {
        int co = co0 + wm * 64 + mi * 16 + (l >> 4) * 4 + rr;
        op[(long)co * NDIM + nn] = acc[mi][nj][rr];
      }
    }
  }
}

// ---- epilogue: out[s][co][pq] = (sum_kq Opart + b[co]*BF(s,p,q)) * fin
__global__ __launch_bounds__(256) void epi_kernel(const float* __restrict__ Opart,
                                                  const float* __restrict__ bb,
                                                  const float* __restrict__ cb,
                                                  float* __restrict__ out) {
  int t4 = blockIdx.x * 256 + threadIdx.x;   // 131072 threads, 4 floats each
  int base = t4 * 4;                         // = s*8192 + co*16 + p*4 (+q lanes)
  int s = base >> 13;
  int co = (base >> 4) & 511;
  int p = (base >> 2) & 3;
  long osrc = (long)co * NDIM + s * 16 + p * 4;
  f32x4 v = *(const f32x4*)(Opart + osrc);
  #pragma unroll
  for (int kq = 1; kq < KQ; ++kq)
    v += *(const f32x4*)(Opart + (long)kq * CCH * NDIM + osrc);
  f32x4 bf4 = {0.f, 0.f, 0.f, 0.f};
  #pragma unroll
  for (int i = 0; i < 3; ++i) {
    int n = i * 64 + s;
    float Sy = axis_sum(bb[n * 4 + 1], bb[n * 4 + 3], p);
    #pragma unroll
    for (int q = 0; q < 4; ++q)
      bf4[q] += Sy * axis_sum(bb[n * 4 + 0], bb[n * 4 + 2], q);
  }
  const float fin = 1.f / (3.f * 512.f * 16.f);
  v = (v + cb[co] * bf4) * fin;
  *(f32x4*)(out + base) = v;
}

extern "C" void kernel_launch(void* const* d_in, const int* in_sizes, int n_in,
                              void* d_out, int out_size, void* d_ws, size_t ws_size,
                              hipStream_t stream) {
  const float* feat = (const float*)d_in[0];
  const float* bb = (const float*)d_in[1];
  const float* cw = (const float*)d_in[2];
  const float* cb = (const float*)d_in[3];
  float* out = (float*)d_out;

  const size_t WB_BYTES = (size_t)CCH * 9 * CCH * 2;            //   4,718,592
  const size_t GB_BYTES = (size_t)NDIM * KDIM * 2;              //   9,437,184
  const size_t OP_BYTES = (size_t)KQ * CCH * NDIM * 4;          //  16,777,216
  if (ws_size < WB_BYTES + GB_BYTES + OP_BYTES) return;

  char* ws = (char*)d_ws;
  bf16* Wb = (bf16*)ws;
  bf16* Gb = (bf16*)(ws + WB_BYTES);
  float* Opart = (float*)(ws + WB_BYTES + GB_BYTES);

  hipLaunchKernelGGL(wtrans_kernel, dim3(CCH), dim3(256), 0, stream, cw, Wb);
  hipLaunchKernelGGL(pool_feat_kernel, dim3(512), dim3(512), 0, stream, feat, bb, Gb);
  hipLaunchKernelGGL(gemm_kernel, dim3(256), dim3(256), 0, stream, Wb, Gb, Opart);
  hipLaunchKernelGGL(epi_kernel, dim3(512), dim3(256), 0, stream, Opart, bb, cb, out);
}

// Round 18
// 87.269 us; speedup vs baseline: 3.4241x; 1.2336x over previous
//
#include <hip/hip_runtime.h>

// FilterInitializerLinear: conv3x3(512->512, pad1) on (192,512,22,22) fp32,
// PrRoIPool 4x4 per (image,seq) roi, mean over 3 images, /(C*16).
// KEY ALGEBRA: pool FIRST (both ops linear):
//   out[s,co,pq] = (sum_K W[co,K] * G[s,K,pq] + b[co]*Sy[p]*Sx[q]) / (3*512*16)
//   G[ci,ky,kx,p,q] = sum_{u,v} wy_shift[ky][p][u] * wx_shift[kx][q][v] * F[ci][u][v]
// Round-18 (pool only): 32-ci tile (63KB -> 2 blocks/CU, natural cross-block
// stage/compute overlap), b64-pair LDS reads (half the instrs, ~2x fewer bank
// conflicts), rows-only staging (130MB not 193MB), shfl_xor vhalf reduce.

#define NIMG 192
#define CCH 512
#define FH 22
#define FW 22
#define SPATIAL 484
#define KDIM 4608          // pos*512 + ci
#define NDIM 1024          // s*16 + p*4 + q
#define KQ 8               // K-split factor in GEMM
#define KSEG 576           // KDIM / KQ (9 chunks of 64)
#define CISTRIDE 1968      // per-ci LDS bytes (1936 + 32 pad)

typedef __bf16 bf16;
typedef __bf16 bf16x2 __attribute__((ext_vector_type(2)));
typedef __bf16 bf16x8 __attribute__((ext_vector_type(8)));
typedef float f32x2 __attribute__((ext_vector_type(2)));
typedef float f32x4 __attribute__((ext_vector_type(4)));

#define GLOBAL_AS __attribute__((address_space(1)))
#define LDS_AS __attribute__((address_space(3)))

__device__ __forceinline__ void gload_lds16(const void* g, void* l) {
  __builtin_amdgcn_global_load_lds((GLOBAL_AS const void*)g, (LDS_AS void*)l, 16, 0, 0);
}

// Extended read range [r0, r1] for one axis (fp-identical everywhere).
__device__ __forceinline__ void axis_range(float a0, float aw, int& r0, int& r1) {
  const float scale = 1.f / 16.f;
  float s1 = a0 * scale;
  float s2 = (a0 + aw) * scale;
  float bl = (s2 - s1) * 0.25f;
  float endv = (s1 + 3 * bl) + bl;
  int c0 = max(0, (int)floorf(s1));
  int c1 = min(21, (int)floorf(endv) + 1);
  r0 = max(0, c0 - 1);
  r1 = min(21, c1 + 1);
}

// Sum of pooling weights for one (axis, bin) -- for the bias term.
__device__ __forceinline__ float axis_sum(float a0, float aw, int bin) {
  const float scale = 1.f / 16.f;
  float s1 = a0 * scale;
  float s2 = (a0 + aw) * scale;
  float blen = (s2 - s1) * 0.25f;
  float start = s1 + bin * blen;
  float end = start + blen;
  float inv = 1.0f / blen;
  float S = 0.f;
  int s0i = (int)floorf(start);
  for (int kk = 0; kk < 6; ++kk) {
    int cell = s0i + kk;
    float cf = (float)cell;
    float a1 = fmaxf(start, cf);
    float a2 = fmaxf(fminf(end, cf + 1.f), a1);
    float alpha = a1 - cf, lim = a2 - cf;
    float f0 = (lim - 0.5f * lim * lim) - (alpha - 0.5f * alpha * alpha);
    float f1 = 0.5f * lim * lim - 0.5f * alpha * alpha;
    if (cell >= 0 && cell < 22) S += f0 * inv;
    if (cell + 1 >= 0 && cell + 1 < 22) S += f1 * inv;
  }
  return S;
}

// ---- wtrans: conv_w (co,ci,3,3) fp32 -> Wb[co][pos][ci] bf16, via LDS ----
__global__ __launch_bounds__(256) void wtrans_kernel(const float* __restrict__ cw,
                                                     bf16* __restrict__ Wb) {
  __shared__ float lw[CCH * 9];
  int co = blockIdx.x;
  int t = threadIdx.x;
  const float* src = cw + (long)co * CCH * 9;
  #pragma unroll
  for (int k = 0; k < 18; ++k) lw[t + 256 * k] = src[t + 256 * k];
  __syncthreads();
  bf16* dst = Wb + (long)co * 9 * CCH;
  #pragma unroll
  for (int k = 0; k < 18; ++k) {
    int f = t + 256 * k;
    int pos = f >> 9;
    int ci = f & 511;
    dst[f] = (bf16)lw[ci * 9 + pos];
  }
}

// ---- pool_feat: separable PrRoI pooling DIRECT from fp32 NCHW feat,
// summed over 3 images in registers -> Gb[N=s*16+pq][K=pos*512+ci] bf16.
// Grid 1024 = (s 64) x (ciq 16): 32-ci tile = 63KB -> 2 blocks/CU resident
// (block A computes while block B stages = natural overlap).
// 256 threads = 4 waves (wave = p); lane = ci(32) + 32*vhalf.
// Staging: rows [yr0,yr1] only -- 1-2 end-anchored 1KB chunks per ci plane,
// 16B-aligned, clamped in-plane. Compute: v processed in even-aligned PAIRS
// via f32x2 LDS reads (out-of-box partners have zero weight, staged-finite).
__global__ __launch_bounds__(256) void pool_feat_kernel(
    const float* __restrict__ feat, const float* __restrict__ bb,
    bf16* __restrict__ Gb) {
  __shared__ __align__(16) char tileb[32 * CISTRIDE];   // 62,976 B
  __shared__ float wyl[264];    // [3ky][22u][4p] current img
  __shared__ float wxl[264];    // [3kx][22v][4q] current img
  int s = blockIdx.x >> 4;
  int ciq = blockIdx.x & 15;
  int t = threadIdx.x;
  int p = t >> 6;                 // wave id == p
  int lane = t & 63;
  int ci32 = lane & 31;
  int vh = lane >> 5;

  f32x4 A[9];   // [pos = ky*3+kx] over q; summed over imgs (this p, vhalf)
  #pragma unroll
  for (int a = 0; a < 9; ++a) A[a] = (f32x4){0.f, 0.f, 0.f, 0.f};
  const f32x4* wxp = (const f32x4*)wxl;
  const float* tf = (const float*)tileb;

  for (int img = 0; img < 3; ++img) {
    int n = img * 64 + s;
    int yr0, yr1, xr0, xr1;
    axis_range(bb[n * 4 + 1], bb[n * 4 + 3], yr0, yr1);
    axis_range(bb[n * 4 + 0], bb[n * 4 + 2], xr0, xr1);
    __syncthreads();   // previous-img compute done before overwrite
    // stage rows [yr0,yr1] of 32 ci planes: 1-2 x 1KB chunks per ci
    int start16 = (yr0 * 88) & ~15;
    int end16 = ((yr1 + 1) * 88 + 15) & ~15;      // <= 1936
    int cpi = (end16 - start16 + 1023) >> 10;     // 1 or 2
    const float* fpl0 = feat + ((long)n * CCH + ciq * 32) * SPATIAL;
    for (int k = p; k < 32 * cpi; k += 4) {       // wave-uniform k
      int ci = (cpi == 2) ? (k >> 1) : k;
      int c = (cpi == 2) ? (k & 1) : 0;
      int cs = (c == cpi - 1) ? end16 - 1024 : start16;
      if (cs < 0) cs = 0;                          // short-run clamp, in-plane
      gload_lds16((const char*)(fpl0 + (long)ci * SPATIAL) + cs + lane * 16,
                  tileb + ci * CISTRIDE + cs + lane * 16);
    }
    // zero weight tables (separate LDS region; staging still in flight ok)
    for (int idx = t; idx < 528; idx += 256)
      (idx < 264 ? wyl[idx] : wxl[idx - 264]) = 0.f;
    __syncthreads();
    // fill shifted tables: threads 0-7 = (axis, bin); LDS RMW
    if (t < 8) {
      int axis = t >> 2;
      int bin = t & 3;
      const float scale = 1.f / 16.f;
      float a0 = axis ? bb[n * 4 + 0] : bb[n * 4 + 1];
      float aw = axis ? bb[n * 4 + 2] : bb[n * 4 + 3];
      float s1 = a0 * scale;
      float s2 = (a0 + aw) * scale;
      float blen = (s2 - s1) * 0.25f;
      float start = s1 + bin * blen;
      float end = start + blen;
      float inv = 1.0f / blen;
      float* tbl = axis ? wxl : wyl;
      int s0i = (int)floorf(start);
      for (int kk = 0; kk < 6; ++kk) {
        int cell = s0i + kk;
        float cf = (float)cell;
        float a1 = fmaxf(start, cf);
        float a2 = fmaxf(fminf(end, cf + 1.f), a1);
        float alpha = a1 - cf, lim = a2 - cf;
        float f0 = (lim - 0.5f * lim * lim) - (alpha - 0.5f * alpha * alpha);
        float f1 = 0.5f * lim * lim - 0.5f * alpha * alpha;
        if (cell >= 0 && cell < 22) {
          float w = f0 * inv;
          #pragma unroll
          for (int ky = 0; ky < 3; ++ky) {
            int u = cell + ky - 1;
            if (u >= 0 && u < 22) tbl[(ky * 22 + u) * 4 + bin] += w;
          }
        }
        if (cell + 1 >= 0 && cell + 1 < 22) {
          float w = f1 * inv;
          #pragma unroll
          for (int ky = 0; ky < 3; ++ky) {
            int u = cell + ky;
            if (u >= 0 && u < 22) tbl[(ky * 22 + u) * 4 + bin] += w;
          }
        }
      }
    }
    __syncthreads();   // staging drained (vmcnt(0) at barrier) + tables ready

    // v-range split between vhalves at an EVEN boundary (pair-clean)
    int xmid = ((xr0 + xr1 + 2) >> 1) & ~1;
    int v0g = vh ? xmid : (xr0 & ~1);
    int v1g = vh ? xr1 : (xmid - 1);
    const f32x2* pl2 = (const f32x2*)(tf + ci32 * (CISTRIDE / 4));

    for (int vg = v0g; vg <= v1g; vg += 2) {
      float a00 = 0.f, a01 = 0.f, a10 = 0.f, a11 = 0.f, a20 = 0.f, a21 = 0.f;
      for (int u = yr0; u <= yr1; ++u) {
        f32x2 f = pl2[(u * FW + vg) >> 1];        // even offset -> 8B aligned
        float w0 = wyl[u * 4 + p];
        float w1 = wyl[(22 + u) * 4 + p];
        float w2 = wyl[(44 + u) * 4 + p];
        a00 = fmaf(w0, f[0], a00); a01 = fmaf(w0, f[1], a01);
        a10 = fmaf(w1, f[0], a10); a11 = fmaf(w1, f[1], a11);
        a20 = fmaf(w2, f[0], a20); a21 = fmaf(w2, f[1], a21);
      }
      #pragma unroll
      for (int kx = 0; kx < 3; ++kx) {
        f32x4 wx0 = wxp[kx * 22 + vg];
        f32x4 wx1 = wxp[kx * 22 + vg + 1];        // zero outside box
        A[kx] += wx0 * a00 + wx1 * a01;
        A[3 + kx] += wx0 * a10 + wx1 * a11;
        A[6 + kx] += wx0 * a20 + wx1 * a21;
      }
    }
  }

  // cross-vhalf reduce in-wave (lanes l <-> l^32)
  #pragma unroll
  for (int pos = 0; pos < 9; ++pos)
    #pragma unroll
    for (int q = 0; q < 4; ++q)
      A[pos][q] += __shfl_xor(A[pos][q], 32);
  if (vh == 0) {
    int ci = ciq * 32 + ci32;
    #pragma unroll
    for (int pos = 0; pos < 9; ++pos)
      #pragma unroll
      for (int q = 0; q < 4; ++q)
        Gb[(long)(s * 16 + p * 4 + q) * KDIM + pos * CCH + ci] = (bf16)A[pos][q];
  }
}

// ---- gemm: Opart[kq][co 512][n 1024] = W[co][k]*Gb[n][k] over k-segment.
// 256 blocks = 4 mt x 8 nt x 8 kq; 128x128 tile, 4 waves, BK=64, 9 chunks,
// proven staging + both-sides XOR swizzle.
__global__ __launch_bounds__(256, 2) void gemm_kernel(const bf16* __restrict__ Wb,
                                                      const bf16* __restrict__ Gb,
                                                      float* __restrict__ Opart) {
  __shared__ __align__(16) bf16 As[128 * 64];
  __shared__ __align__(16) bf16 Bs[128 * 64];
  int bid = blockIdx.x;
  int kq = bid & 7;
  int nt = (bid >> 3) & 7;
  int mt = bid >> 6;
  int co0 = mt << 7;
  int n0 = nt << 7;
  int kbase = kq * KSEG;

  int tid = threadIdx.x;
  int wv = tid >> 6, l = tid & 63;
  int wm = wv >> 1, wn = wv & 1;
  int lrow = l >> 3;
  int cg8 = ((l & 7) ^ lrow) << 3;

  long aOff[4], bOff[4];
  #pragma unroll
  for (int j = 0; j < 4; ++j) {
    int row = j * 32 + wv * 8 + lrow;
    aOff[j] = (long)(co0 + row) * KDIM + kbase + cg8;
    bOff[j] = (long)(n0 + row) * KDIM + kbase + cg8;
  }

  const f32x4 vz = {0.f, 0.f, 0.f, 0.f};
  f32x4 acc[4][4];
  #pragma unroll
  for (int a = 0; a < 4; ++a)
    #pragma unroll
    for (int b = 0; b < 4; ++b) acc[a][b] = vz;

  for (int c = 0; c < 9; ++c) {
    long sh = c * 64;
    #pragma unroll
    for (int j = 0; j < 4; ++j) {
      gload_lds16(Wb + aOff[j] + sh, (char*)As + (j * 32 + wv * 8) * 128);
      gload_lds16(Gb + bOff[j] + sh, (char*)Bs + (j * 32 + wv * 8) * 128);
    }
    __syncthreads();
    bf16x8 af[2][4], bfv[2][4];
    #pragma unroll
    for (int kk = 0; kk < 2; ++kk) {
      #pragma unroll
      for (int i = 0; i < 4; ++i) {
        int rowa = wm * 64 + i * 16 + (l & 15);
        int offa = rowa * 128 + kk * 64 + ((l >> 4) * 16);
        offa ^= (rowa & 7) << 4;
        af[kk][i] = *(const bf16x8*)((const char*)As + offa);
        int rowb = wn * 64 + i * 16 + (l & 15);
        int offb = rowb * 128 + kk * 64 + ((l >> 4) * 16);
        offb ^= (rowb & 7) << 4;
        bfv[kk][i] = *(const bf16x8*)((const char*)Bs + offb);
      }
    }
    #pragma unroll
    for (int kk = 0; kk < 2; ++kk)
      #pragma unroll
      for (int mi = 0; mi < 4; ++mi)
        #pragma unroll
        for (int nj = 0; nj < 4; ++nj)
          acc[mi][nj] = __builtin_amdgcn_mfma_f32_16x16x32_bf16(
              af[kk][mi], bfv[kk][nj], acc[mi][nj], 0, 0, 0);
    __syncthreads();
  }

  // C/D layout: col=lane&15 (n), row=(lane>>4)*4+reg (co)
  float* op = Opart + (long)kq * CCH * NDIM;
  #pragma unroll
  for (int nj = 0; nj < 4; ++nj) {
    int nn = n0 + wn * 64 + nj * 16 + (l & 15);
    #pragma unroll
    for (int mi = 0; mi < 4; ++mi) {
      #pragma unroll
      for (int rr = 0; rr < 4; ++rr) {
        int co = co0 + wm * 64 + mi * 16 + (l >> 4) * 4 + rr;
        op[(long)co * NDIM + nn] = acc[mi][nj][rr];
      }
    }
  }
}

// ---- epilogue: out[s][co][pq] = (sum_kq Opart + b[co]*BF(s,p,q)) * fin
__global__ __launch_bounds__(256) void epi_kernel(const float* __restrict__ Opart,
                                                  const float* __restrict__ bb,
                                                  const float* __restrict__ cb,
                                                  float* __restrict__ out) {
  int t4 = blockIdx.x * 256 + threadIdx.x;   // 131072 threads, 4 floats each
  int base = t4 * 4;                         // = s*8192 + co*16 + p*4 (+q lanes)
  int s = base >> 13;
  int co = (base >> 4) & 511;
  int p = (base >> 2) & 3;
  long osrc = (long)co * NDIM + s * 16 + p * 4;
  f32x4 v = *(const f32x4*)(Opart + osrc);
  #pragma unroll
  for (int kq = 1; kq < KQ; ++kq)
    v += *(const f32x4*)(Opart + (long)kq * CCH * NDIM + osrc);
  f32x4 bf4 = {0.f, 0.f, 0.f, 0.f};
  #pragma unroll
  for (int i = 0; i < 3; ++i) {
    int n = i * 64 + s;
    float Sy = axis_sum(bb[n * 4 + 1], bb[n * 4 + 3], p);
    #pragma unroll
    for (int q = 0; q < 4; ++q)
      bf4[q] += Sy * axis_sum(bb[n * 4 + 0], bb[n * 4 + 2], q);
  }
  const float fin = 1.f / (3.f * 512.f * 16.f);
  v = (v + cb[co] * bf4) * fin;
  *(f32x4*)(out + base) = v;
}

extern "C" void kernel_launch(void* const* d_in, const int* in_sizes, int n_in,
                              void* d_out, int out_size, void* d_ws, size_t ws_size,
                              hipStream_t stream) {
  const float* feat = (const float*)d_in[0];
  const float* bb = (const float*)d_in[1];
  const float* cw = (const float*)d_in[2];
  const float* cb = (const float*)d_in[3];
  float* out = (float*)d_out;

  const size_t WB_BYTES = (size_t)CCH * 9 * CCH * 2;            //   4,718,592
  const size_t GB_BYTES = (size_t)NDIM * KDIM * 2;              //   9,437,184
  const size_t OP_BYTES = (size_t)KQ * CCH * NDIM * 4;          //  16,777,216
  if (ws_size < WB_BYTES + GB_BYTES + OP_BYTES) return;

  char* ws = (char*)d_ws;
  bf16* Wb = (bf16*)ws;
  bf16* Gb = (bf16*)(ws + WB_BYTES);
  float* Opart = (float*)(ws + WB_BYTES + GB_BYTES);

  hipLaunchKernelGGL(wtrans_kernel, dim3(CCH), dim3(256), 0, stream, cw, Wb);
  hipLaunchKernelGGL(pool_feat_kernel, dim3(1024), dim3(256), 0, stream, feat, bb, Gb);
  hipLaunchKernelGGL(gemm_kernel, dim3(256), dim3(256), 0, stream, Wb, Gb, Opart);
  hipLaunchKernelGGL(epi_kernel, dim3(512), dim3(256), 0, stream, Opart, bb, cb, out);
}

// Round 19
// 79.846 us; speedup vs baseline: 3.7425x; 1.0930x over previous
//
#include <hip/hip_runtime.h>

// FilterInitializerLinear: conv3x3(512->512, pad1) on (192,512,22,22) fp32,
// PrRoIPool 4x4 per (image,seq) roi, mean over 3 images, /(C*16).
// KEY ALGEBRA: pool FIRST (both ops linear):
//   out[s,co,pq] = (sum_K W[co,K] * G[s,K,pq] + b[co]*Sy[p]*Sx[q]) / (3*512*16)
//   G[ci,ky,kx,p,q] = sum_{u,v} wy_shift[ky][p][u] * wx_shift[kx][q][v] * F[ci][u][v]
// Round-18: 16-ci tiles (33.6KB -> 4 blocks/CU, deeper cross-block
// stage/compute overlap; lane = ci16 x vquarter, shfl_xor reduce) and wtrans
// fused into the pool kernel (blocks >= 2048; reuses tile LDS). 3 launches.

#define NIMG 192
#define CCH 512
#define FH 22
#define FW 22
#define SPATIAL 484
#define KDIM 4608          // pos*512 + ci
#define NDIM 1024          // s*16 + p*4 + q
#define KQ 8               // K-split factor in GEMM
#define KSEG 576           // KDIM / KQ (9 chunks of 64)
#define CISTRIDE 1968      // per-ci LDS bytes (1936 + 32 pad)
#define POOLBLKS 2048      // 64 s x 32 ciq

typedef __bf16 bf16;
typedef __bf16 bf16x2 __attribute__((ext_vector_type(2)));
typedef __bf16 bf16x8 __attribute__((ext_vector_type(8)));
typedef float f32x2 __attribute__((ext_vector_type(2)));
typedef float f32x4 __attribute__((ext_vector_type(4)));

#define GLOBAL_AS __attribute__((address_space(1)))
#define LDS_AS __attribute__((address_space(3)))

__device__ __forceinline__ void gload_lds16(const void* g, void* l) {
  __builtin_amdgcn_global_load_lds((GLOBAL_AS const void*)g, (LDS_AS void*)l, 16, 0, 0);
}

// Extended read range [r0, r1] for one axis (fp-identical everywhere).
__device__ __forceinline__ void axis_range(float a0, float aw, int& r0, int& r1) {
  const float scale = 1.f / 16.f;
  float s1 = a0 * scale;
  float s2 = (a0 + aw) * scale;
  float bl = (s2 - s1) * 0.25f;
  float endv = (s1 + 3 * bl) + bl;
  int c0 = max(0, (int)floorf(s1));
  int c1 = min(21, (int)floorf(endv) + 1);
  r0 = max(0, c0 - 1);
  r1 = min(21, c1 + 1);
}

// Sum of pooling weights for one (axis, bin) -- for the bias term.
__device__ __forceinline__ float axis_sum(float a0, float aw, int bin) {
  const float scale = 1.f / 16.f;
  float s1 = a0 * scale;
  float s2 = (a0 + aw) * scale;
  float blen = (s2 - s1) * 0.25f;
  float start = s1 + bin * blen;
  float end = start + blen;
  float inv = 1.0f / blen;
  float S = 0.f;
  int s0i = (int)floorf(start);
  for (int kk = 0; kk < 6; ++kk) {
    int cell = s0i + kk;
    float cf = (float)cell;
    float a1 = fmaxf(start, cf);
    float a2 = fmaxf(fminf(end, cf + 1.f), a1);
    float alpha = a1 - cf, lim = a2 - cf;
    float f0 = (lim - 0.5f * lim * lim) - (alpha - 0.5f * alpha * alpha);
    float f1 = 0.5f * lim * lim - 0.5f * alpha * alpha;
    if (cell >= 0 && cell < 22) S += f0 * inv;
    if (cell + 1 >= 0 && cell + 1 < 22) S += f1 * inv;
  }
  return S;
}

// ---- pool_feat (+ fused wtrans): separable PrRoI pooling DIRECT from fp32
// NCHW feat, summed over 3 images in registers -> Gb[N][K] bf16.
// Blocks [0, 2048): pool. 16-ci tile = 33.6KB LDS -> 4 blocks/CU.
// 256 threads = 4 waves (wave = p); lane = ci16(16) + 16*vquarter(4).
// Staging: rows [yr0,yr1], 1-2 end-anchored 1KB chunks per ci plane.
// Compute: even-aligned v-pairs via f32x2 LDS reads, pairs strided 4-way
// across vquarters; shfl_xor(16/32) reduce.
// Blocks [2048, 2560): conv_w (co,ci,3,3) -> Wb[co][pos][ci] bf16.
__global__ __launch_bounds__(256, 4) void pool_feat_kernel(
    const float* __restrict__ feat, const float* __restrict__ bb,
    const float* __restrict__ cw, bf16* __restrict__ Wb,
    bf16* __restrict__ Gb) {
  __shared__ __align__(16) char tileb[16 * CISTRIDE];   // 31,488 B
  __shared__ float wyl[264];    // [3ky][22u][4p] current img
  __shared__ float wxl[264];    // [3kx][22v][4q] current img
  int t = threadIdx.x;
  if (blockIdx.x >= POOLBLKS) {              // fused wtrans
    int co = blockIdx.x - POOLBLKS;
    float* lw = (float*)tileb;               // 18,432 B scratch
    const float* src = cw + (long)co * CCH * 9;
    #pragma unroll
    for (int k = 0; k < 18; ++k) lw[t + 256 * k] = src[t + 256 * k];
    __syncthreads();
    bf16* dst = Wb + (long)co * 9 * CCH;
    #pragma unroll
    for (int k = 0; k < 18; ++k) {
      int f = t + 256 * k;
      int pos = f >> 9;
      int ci = f & 511;
      dst[f] = (bf16)lw[ci * 9 + pos];
    }
    return;
  }
  int s = blockIdx.x >> 5;
  int ciq = blockIdx.x & 31;
  int p = t >> 6;                 // wave id == p
  int lane = t & 63;
  int ci16 = lane & 15;
  int vq = lane >> 4;             // v-quarter

  f32x4 A[9];   // [pos = ky*3+kx] over q; summed over imgs (this p, vq)
  #pragma unroll
  for (int a = 0; a < 9; ++a) A[a] = (f32x4){0.f, 0.f, 0.f, 0.f};
  const f32x4* wxp = (const f32x4*)wxl;
  const float* tf = (const float*)tileb;

  for (int img = 0; img < 3; ++img) {
    int n = img * 64 + s;
    int yr0, yr1, xr0, xr1;
    axis_range(bb[n * 4 + 1], bb[n * 4 + 3], yr0, yr1);
    axis_range(bb[n * 4 + 0], bb[n * 4 + 2], xr0, xr1);
    __syncthreads();   // previous-img compute done before overwrite
    // stage rows [yr0,yr1] of 16 ci planes: 1-2 x 1KB chunks per ci
    int start16 = (yr0 * 88) & ~15;
    int end16 = ((yr1 + 1) * 88 + 15) & ~15;      // <= 1936
    int cpi = (end16 - start16 + 1023) >> 10;     // 1 or 2
    const float* fpl0 = feat + ((long)n * CCH + ciq * 16) * SPATIAL;
    for (int k = p; k < 16 * cpi; k += 4) {       // wave-uniform k
      int ci = (cpi == 2) ? (k >> 1) : k;
      int c = (cpi == 2) ? (k & 1) : 0;
      int cs = (c == cpi - 1) ? end16 - 1024 : start16;
      if (cs < 0) cs = 0;                          // short-run clamp, in-plane
      gload_lds16((const char*)(fpl0 + (long)ci * SPATIAL) + cs + lane * 16,
                  tileb + ci * CISTRIDE + cs + lane * 16);
    }
    // zero weight tables (separate LDS region; staging still in flight ok)
    for (int idx = t; idx < 528; idx += 256)
      (idx < 264 ? wyl[idx] : wxl[idx - 264]) = 0.f;
    __syncthreads();
    // fill shifted tables: threads 0-7 = (axis, bin); LDS RMW
    if (t < 8) {
      int axis = t >> 2;
      int bin = t & 3;
      const float scale = 1.f / 16.f;
      float a0 = axis ? bb[n * 4 + 0] : bb[n * 4 + 1];
      float aw = axis ? bb[n * 4 + 2] : bb[n * 4 + 3];
      float s1 = a0 * scale;
      float s2 = (a0 + aw) * scale;
      float blen = (s2 - s1) * 0.25f;
      float start = s1 + bin * blen;
      float end = start + blen;
      float inv = 1.0f / blen;
      float* tbl = axis ? wxl : wyl;
      int s0i = (int)floorf(start);
      for (int kk = 0; kk < 6; ++kk) {
        int cell = s0i + kk;
        float cf = (float)cell;
        float a1 = fmaxf(start, cf);
        float a2 = fmaxf(fminf(end, cf + 1.f), a1);
        float alpha = a1 - cf, lim = a2 - cf;
        float f0 = (lim - 0.5f * lim * lim) - (alpha - 0.5f * alpha * alpha);
        float f1 = 0.5f * lim * lim - 0.5f * alpha * alpha;
        if (cell >= 0 && cell < 22) {
          float w = f0 * inv;
          #pragma unroll
          for (int ky = 0; ky < 3; ++ky) {
            int u = cell + ky - 1;
            if (u >= 0 && u < 22) tbl[(ky * 22 + u) * 4 + bin] += w;
          }
        }
        if (cell + 1 >= 0 && cell + 1 < 22) {
          float w = f1 * inv;
          #pragma unroll
          for (int ky = 0; ky < 3; ++ky) {
            int u = cell + ky;
            if (u >= 0 && u < 22) tbl[(ky * 22 + u) * 4 + bin] += w;
          }
        }
      }
    }
    __syncthreads();   // staging drained (vmcnt(0) at barrier) + tables ready

    // v processed in even-aligned pairs; pairs strided 4-way across vquarters
    int vbase = xr0 & ~1;
    int npairs = ((xr1 - vbase) >> 1) + 1;
    const f32x2* pl2 = (const f32x2*)(tf + ci16 * (CISTRIDE / 4));

    for (int j = vq; j < npairs; j += 4) {
      int vg = vbase + 2 * j;
      float a00 = 0.f, a01 = 0.f, a10 = 0.f, a11 = 0.f, a20 = 0.f, a21 = 0.f;
      for (int u = yr0; u <= yr1; ++u) {
        f32x2 f = pl2[(u * FW + vg) >> 1];        // even offset -> 8B aligned
        float w0 = wyl[u * 4 + p];
        float w1 = wyl[(22 + u) * 4 + p];
        float w2 = wyl[(44 + u) * 4 + p];
        a00 = fmaf(w0, f[0], a00); a01 = fmaf(w0, f[1], a01);
        a10 = fmaf(w1, f[0], a10); a11 = fmaf(w1, f[1], a11);
        a20 = fmaf(w2, f[0], a20); a21 = fmaf(w2, f[1], a21);
      }
      #pragma unroll
      for (int kx = 0; kx < 3; ++kx) {
        f32x4 wx0 = wxp[kx * 22 + vg];
        f32x4 wx1 = wxp[kx * 22 + vg + 1];        // zero outside box
        A[kx] += wx0 * a00 + wx1 * a01;
        A[3 + kx] += wx0 * a10 + wx1 * a11;
        A[6 + kx] += wx0 * a20 + wx1 * a21;
      }
    }
  }

  // cross-vquarter reduce in-wave (lane bits 4 and 5)
  #pragma unroll
  for (int pos = 0; pos < 9; ++pos) {
    #pragma unroll
    for (int q = 0; q < 4; ++q) {
      A[pos][q] += __shfl_xor(A[pos][q], 16);
      A[pos][q] += __shfl_xor(A[pos][q], 32);
    }
  }
  if (vq == 0) {
    int ci = ciq * 16 + ci16;
    #pragma unroll
    for (int pos = 0; pos < 9; ++pos)
      #pragma unroll
      for (int q = 0; q < 4; ++q)
        Gb[(long)(s * 16 + p * 4 + q) * KDIM + pos * CCH + ci] = (bf16)A[pos][q];
  }
}

// ---- gemm: Opart[kq][co 512][n 1024] = W[co][k]*Gb[n][k] over k-segment.
// 256 blocks = 4 mt x 8 nt x 8 kq; 128x128 tile, 4 waves, BK=64, 9 chunks,
// proven staging + both-sides XOR swizzle.
__global__ __launch_bounds__(256, 2) void gemm_kernel(const bf16* __restrict__ Wb,
                                                      const bf16* __restrict__ Gb,
                                                      float* __restrict__ Opart) {
  __shared__ __align__(16) bf16 As[128 * 64];
  __shared__ __align__(16) bf16 Bs[128 * 64];
  int bid = blockIdx.x;
  int kq = bid & 7;
  int nt = (bid >> 3) & 7;
  int mt = bid >> 6;
  int co0 = mt << 7;
  int n0 = nt << 7;
  int kbase = kq * KSEG;

  int tid = threadIdx.x;
  int wv = tid >> 6, l = tid & 63;
  int wm = wv >> 1, wn = wv & 1;
  int lrow = l >> 3;
  int cg8 = ((l & 7) ^ lrow) << 3;

  long aOff[4], bOff[4];
  #pragma unroll
  for (int j = 0; j < 4; ++j) {
    int row = j * 32 + wv * 8 + lrow;
    aOff[j] = (long)(co0 + row) * KDIM + kbase + cg8;
    bOff[j] = (long)(n0 + row) * KDIM + kbase + cg8;
  }

  const f32x4 vz = {0.f, 0.f, 0.f, 0.f};
  f32x4 acc[4][4];
  #pragma unroll
  for (int a = 0; a < 4; ++a)
    #pragma unroll
    for (int b = 0; b < 4; ++b) acc[a][b] = vz;

  for (int c = 0; c < 9; ++c) {
    long sh = c * 64;
    #pragma unroll
    for (int j = 0; j < 4; ++j) {
      gload_lds16(Wb + aOff[j] + sh, (char*)As + (j * 32 + wv * 8) * 128);
      gload_lds16(Gb + bOff[j] + sh, (char*)Bs + (j * 32 + wv * 8) * 128);
    }
    __syncthreads();
    bf16x8 af[2][4], bfv[2][4];
    #pragma unroll
    for (int kk = 0; kk < 2; ++kk) {
      #pragma unroll
      for (int i = 0; i < 4; ++i) {
        int rowa = wm * 64 + i * 16 + (l & 15);
        int offa = rowa * 128 + kk * 64 + ((l >> 4) * 16);
        offa ^= (rowa & 7) << 4;
        af[kk][i] = *(const bf16x8*)((const char*)As + offa);
        int rowb = wn * 64 + i * 16 + (l & 15);
        int offb = rowb * 128 + kk * 64 + ((l >> 4) * 16);
        offb ^= (rowb & 7) << 4;
        bfv[kk][i] = *(const bf16x8*)((const char*)Bs + offb);
      }
    }
    #pragma unroll
    for (int kk = 0; kk < 2; ++kk)
      #pragma unroll
      for (int mi = 0; mi < 4; ++mi)
        #pragma unroll
        for (int nj = 0; nj < 4; ++nj)
          acc[mi][nj] = __builtin_amdgcn_mfma_f32_16x16x32_bf16(
              af[kk][mi], bfv[kk][nj], acc[mi][nj], 0, 0, 0);
    __syncthreads();
  }

  // C/D layout: col=lane&15 (n), row=(lane>>4)*4+reg (co)
  float* op = Opart + (long)kq * CCH * NDIM;
  #pragma unroll
  for (int nj = 0; nj < 4; ++nj) {
    int nn = n0 + wn * 64 + nj * 16 + (l & 15);
    #pragma unroll
    for (int mi = 0; mi < 4; ++mi) {
      #pragma unroll
      for (int rr = 0; rr < 4; ++rr) {
        int co = co0 + wm * 64 + mi * 16 + (l >> 4) * 4 + rr;
        op[(long)co * NDIM + nn] = acc[mi][nj][rr];
      }
    }
  }
}

// ---- epilogue: out[s][co][pq] = (sum_kq Opart + b[co]*BF(s,p,q)) * fin
__global__ __launch_bounds__(256) void epi_kernel(const float* __restrict__ Opart,
                                                  const float* __restrict__ bb,
                                                  const float* __restrict__ cb,
                                                  float* __restrict__ out) {
  int t4 = blockIdx.x * 256 + threadIdx.x;   // 131072 threads, 4 floats each
  int base = t4 * 4;                         // = s*8192 + co*16 + p*4 (+q lanes)
  int s = base >> 13;
  int co = (base >> 4) & 511;
  int p = (base >> 2) & 3;
  long osrc = (long)co * NDIM + s * 16 + p * 4;
  f32x4 v = *(const f32x4*)(Opart + osrc);
  #pragma unroll
  for (int kq = 1; kq < KQ; ++kq)
    v += *(const f32x4*)(Opart + (long)kq * CCH * NDIM + osrc);
  f32x4 bf4 = {0.f, 0.f, 0.f, 0.f};
  #pragma unroll
  for (int i = 0; i < 3; ++i) {
    int n = i * 64 + s;
    float Sy = axis_sum(bb[n * 4 + 1], bb[n * 4 + 3], p);
    #pragma unroll
    for (int q = 0; q < 4; ++q)
      bf4[q] += Sy * axis_sum(bb[n * 4 + 0], bb[n * 4 + 2], q);
  }
  const float fin = 1.f / (3.f * 512.f * 16.f);
  v = (v + cb[co] * bf4) * fin;
  *(f32x4*)(out + base) = v;
}

extern "C" void kernel_launch(void* const* d_in, const int* in_sizes, int n_in,
                              void* d_out, int out_size, void* d_ws, size_t ws_size,
                              hipStream_t stream) {
  const float* feat = (const float*)d_in[0];
  const float* bb = (const float*)d_in[1];
  const float* cw = (const float*)d_in[2];
  const float* cb = (const float*)d_in[3];
  float* out = (float*)d_out;

  const size_t WB_BYTES = (size_t)CCH * 9 * CCH * 2;            //   4,718,592
  const size_t GB_BYTES = (size_t)NDIM * KDIM * 2;              //   9,437,184
  const size_t OP_BYTES = (size_t)KQ * CCH * NDIM * 4;          //  16,777,216
  if (ws_size < WB_BYTES + GB_BYTES + OP_BYTES) return;

  char* ws = (char*)d_ws;
  bf16* Wb = (bf16*)ws;
  bf16* Gb = (bf16*)(ws + WB_BYTES);
  float* Opart = (float*)(ws + WB_BYTES + GB_BYTES);

  hipLaunchKernelGGL(pool_feat_kernel, dim3(POOLBLKS + CCH), dim3(256), 0, stream,
                     feat, bb, cw, Wb, Gb);
  hipLaunchKernelGGL(gemm_kernel, dim3(256), dim3(256), 0, stream, Wb, Gb, Opart);
  hipLaunchKernelGGL(epi_kernel, dim3(512), dim3(256), 0, stream, Opart, bb, cb, out);
}